// Round 2
// baseline (1397.688 us; speedup 1.0000x reference)
//
#include <hip/hip_runtime.h>

#define EPSV 1e-5f

typedef __attribute__((ext_vector_type(8))) short v8s;
typedef __attribute__((ext_vector_type(4))) float v4f;

__device__ __forceinline__ unsigned short f2bf(float f){
  unsigned int u = __float_as_uint(f);
  u += 0x7FFF + ((u >> 16) & 1);
  return (unsigned short)(u >> 16);
}
__device__ __forceinline__ void bf2x(unsigned int u, float& lo, float& hi){
  lo = __uint_as_float(u << 16);
  hi = __uint_as_float(u & 0xffff0000u);
}

// ---------------- preprocessing ----------------
// NOTE: harness passes integer inputs as int32 (edge_index is [2,E] int32 here).
__global__ void k_init(float* deg, int* cnt, int N){
  int i = blockIdx.x*256 + threadIdx.x;
  if (i < N){ deg[i] = 1.0f; cnt[i] = 0; }   // deg=1: self-loop weight
}

__global__ void k_deg(const int* ei, const float* ew, float* deg, int* cnt, int E){
  int e = blockIdx.x*256 + threadIdx.x;
  if (e < E){
    int c = ei[E + e];
    atomicAdd(&deg[c], ew[e]);
    atomicAdd(&cnt[c], 1);
  }
}

__global__ void k_dis(const float* deg, float* dis, int N){
  int i = blockIdx.x*256 + threadIdx.x;
  if (i < N) dis[i] = rsqrtf(deg[i]);   // deg >= 1 always
}

__global__ void k_scan(const int* cnt, int* offs, int N){
  __shared__ int sm[1024];
  int t = threadIdx.x;
  int C = (N + 1023) >> 10;
  int base = t * C;
  int s = 0;
  for (int j = 0; j < C; j++){ int idx = base + j; if (idx < N) s += cnt[idx]; }
  sm[t] = s;
  __syncthreads();
  for (int off = 1; off < 1024; off <<= 1){
    int v = (t >= off) ? sm[t - off] : 0;
    __syncthreads();
    sm[t] += v;
    __syncthreads();
  }
  int run = sm[t] - s;   // exclusive prefix
  for (int j = 0; j < C; j++){
    int idx = base + j;
    if (idx <= N){
      offs[idx] = run;
      if (idx < N) run += cnt[idx];
    }
  }
}

// cnt is reused as the per-node cursor (zeroed by k_zero before this runs)
__global__ void k_bucket(const int* ei, const float* ew, const float* dis, const int* offs,
                         int* cursor, int2* ep, int E){
  int e = blockIdx.x*256 + threadIdx.x;
  if (e < E){
    int r = ei[e], c = ei[E + e];
    float nrm = dis[r] * ew[e] * dis[c];
    int pos = offs[c] + atomicAdd(&cursor[c], 1);
    ep[pos] = make_int2(r, __float_as_int(nrm));
  }
}

__global__ void k_zero(int* p, int N){
  int i = blockIdx.x*256 + threadIdx.x;
  if (i < N) p[i] = 0;
}

// transpose + bf16-convert all weights: [WT1|WT2|WTc0|WTc1|WTc2|WTlast], each [n][k], k-stride 256
__global__ void k_wt(const float* W1, const float* W2, const float* Wc, const float* Wl,
                     unsigned short* WT){
  int t = blockIdx.x*256 + threadIdx.x;   // 65536 threads
  int k = t >> 8, n = t & 255;
  WT[0*65536 + n*256 + k] = f2bf(W1[k*256 + n]);
  WT[1*65536 + n*256 + k] = f2bf(W2[k*256 + n]);
  WT[2*65536 + n*256 + k] = f2bf(Wc[0*65536 + k*256 + n]);
  WT[3*65536 + n*256 + k] = f2bf(Wc[1*65536 + k*256 + n]);
  WT[4*65536 + n*256 + k] = f2bf(Wc[2*65536 + k*256 + n]);
  if (n < 128) WT[5*65536 + n*256 + k] = f2bf(Wl[k*128 + n]);
}

// ---------------- bf16 MFMA GEMM: C[M,Nout] = A[M,256] * W[256,Nout], WT passed as [Nout][256] ----------------
template<bool ABF16, bool OUTBF16, bool BIAS, bool RELU>
__global__ __launch_bounds__(256, 2) void k_gemm(const void* Ap, const unsigned short* WT,
    const float* bias, void* Cp, int M, int Nout){
  __shared__ unsigned short As[128][40];
  __shared__ unsigned short Bs[128][40];
  const int tid  = threadIdx.x;
  const int lane = tid & 63, wv = tid >> 6;
  const int wm = wv >> 1, wn = wv & 1;
  const int quad = lane >> 4, m16 = lane & 15;
  const int bm = blockIdx.x, bn = blockIdx.y;
  const int srow = tid >> 1, sseg = (tid & 1) * 16;
  const int arow_g = min(bm*128 + srow, M - 1);

  v4f acc[4][4];
  #pragma unroll
  for (int a = 0; a < 4; a++)
    #pragma unroll
    for (int b = 0; b < 4; b++) acc[a][b] = (v4f)(0.0f);

  const float* Af = (const float*)Ap;
  const unsigned short* Ab = (const unsigned short*)Ap;

  for (int ks = 0; ks < 256; ks += 32){
    __syncthreads();
    if constexpr (ABF16){
      const unsigned short* src = Ab + (size_t)arow_g*256 + ks + sseg;
      uint4 u0 = *(const uint4*)(src);
      uint4 u1 = *(const uint4*)(src + 8);
      *(uint4*)&As[srow][sseg]     = u0;
      *(uint4*)&As[srow][sseg + 8] = u1;
    } else {
      const float* src = Af + (size_t)arow_g*256 + ks + sseg;
      float4 v0 = *(const float4*)(src + 0);
      float4 v1 = *(const float4*)(src + 4);
      float4 v2 = *(const float4*)(src + 8);
      float4 v3 = *(const float4*)(src + 12);
      uint4 q0, q1;
      q0.x = f2bf(v0.x) | ((unsigned)f2bf(v0.y) << 16);
      q0.y = f2bf(v0.z) | ((unsigned)f2bf(v0.w) << 16);
      q0.z = f2bf(v1.x) | ((unsigned)f2bf(v1.y) << 16);
      q0.w = f2bf(v1.z) | ((unsigned)f2bf(v1.w) << 16);
      q1.x = f2bf(v2.x) | ((unsigned)f2bf(v2.y) << 16);
      q1.y = f2bf(v2.z) | ((unsigned)f2bf(v2.w) << 16);
      q1.z = f2bf(v3.x) | ((unsigned)f2bf(v3.y) << 16);
      q1.w = f2bf(v3.z) | ((unsigned)f2bf(v3.w) << 16);
      *(uint4*)&As[srow][sseg]     = q0;
      *(uint4*)&As[srow][sseg + 8] = q1;
    }
    {
      const unsigned short* src = WT + (size_t)(bn*128 + srow)*256 + ks + sseg;
      uint4 u0 = *(const uint4*)(src);
      uint4 u1 = *(const uint4*)(src + 8);
      *(uint4*)&Bs[srow][sseg]     = u0;
      *(uint4*)&Bs[srow][sseg + 8] = u1;
    }
    __syncthreads();

    v8s af[4], bfr[4];
    #pragma unroll
    for (int tm = 0; tm < 4; tm++) af[tm]  = *(const v8s*)&As[wm*64 + tm*16 + m16][quad*8];
    #pragma unroll
    for (int tn = 0; tn < 4; tn++) bfr[tn] = *(const v8s*)&Bs[wn*64 + tn*16 + m16][quad*8];
    #pragma unroll
    for (int tm = 0; tm < 4; tm++)
      #pragma unroll
      for (int tn = 0; tn < 4; tn++)
        acc[tm][tn] = __builtin_amdgcn_mfma_f32_16x16x32_bf16(af[tm], bfr[tn], acc[tm][tn], 0, 0, 0);
  }

  #pragma unroll
  for (int tn = 0; tn < 4; tn++){
    int col = bn*128 + wn*64 + tn*16 + m16;
    float bv = BIAS ? bias[col] : 0.0f;
    #pragma unroll
    for (int tm = 0; tm < 4; tm++){
      int row0 = bm*128 + wm*64 + tm*16 + quad*4;
      #pragma unroll
      for (int r = 0; r < 4; r++){
        int row = row0 + r;
        if (row < M){
          float v = acc[tm][tn][r] + bv;
          if (RELU) v = fmaxf(v, 0.0f);
          if (OUTBF16) ((unsigned short*)Cp)[(size_t)row*Nout + col] = f2bf(v);
          else         ((float*)Cp)[(size_t)row*Nout + col] = v;
        }
      }
    }
  }
}

// ---------------- LayerNorm (one wave per node) ----------------
__global__ __launch_bounds__(256) void k_ln(const float* h, const float* g, const float* b,
                                            unsigned short* nf, int N){
  const int lane = threadIdx.x & 63, wv = threadIdx.x >> 6;
  const int i = blockIdx.x*4 + wv;
  if (i >= N) return;
  const float* row = h + (size_t)i*256;
  float4 v = *(const float4*)(row + lane*4);
  float s = v.x + v.y + v.z + v.w;
  float q = v.x*v.x + v.y*v.y + v.z*v.z + v.w*v.w;
  for (int off = 32; off > 0; off >>= 1){
    s += __shfl_xor(s, off, 64);
    q += __shfl_xor(q, off, 64);
  }
  float mean = s * (1.0f/256.0f);
  float var  = q * (1.0f/256.0f) - mean*mean;
  float rs = rsqrtf(var + EPSV);
  int c = lane*4;
  ushort4 st;
  st.x = f2bf((v.x - mean)*rs*g[c+0] + b[c+0]);
  st.y = f2bf((v.y - mean)*rs*g[c+1] + b[c+1]);
  st.z = f2bf((v.z - mean)*rs*g[c+2] + b[c+2]);
  st.w = f2bf((v.w - mean)*rs*g[c+3] + b[c+3]);
  *(ushort4*)(nf + (size_t)i*256 + c) = st;
}

// ---------------- CSR aggregation: one wave per destination node ----------------
template<int D, bool BIAS>
__global__ __launch_bounds__(256) void k_agg(const unsigned short* xw, const int2* ep,
    const int* offs, const float* dis, const float* bias, float* out, int N){
  constexpr int V = D / 64;
  const int lane = threadIdx.x & 63, wv = threadIdx.x >> 6;
  const int i = blockIdx.x*4 + wv;
  if (i >= N) return;
  float acc[V];
  float dsi = dis[i];
  float coef = dsi * dsi;   // self-loop norm
  {
    const unsigned short* r = xw + (size_t)i*D + lane*V;
    if constexpr (V == 4){
      uint2 u = *(const uint2*)r;
      float a,b2,c,d; bf2x(u.x,a,b2); bf2x(u.y,c,d);
      acc[0]=coef*a; acc[1]=coef*b2; acc[2]=coef*c; acc[3]=coef*d;
    } else {
      unsigned int u = *(const unsigned int*)r;
      float a,b2; bf2x(u,a,b2);
      acc[0]=coef*a; acc[1]=coef*b2;
    }
  }
  int e0 = offs[i], e1 = offs[i+1];
  for (int e = e0; e < e1; e++){
    int2 p = ep[e];
    float nr = __int_as_float(p.y);
    const unsigned short* r = xw + (size_t)p.x*D + lane*V;
    if constexpr (V == 4){
      uint2 u = *(const uint2*)r;
      float a,b2,c,d; bf2x(u.x,a,b2); bf2x(u.y,c,d);
      acc[0]=fmaf(nr,a,acc[0]); acc[1]=fmaf(nr,b2,acc[1]);
      acc[2]=fmaf(nr,c,acc[2]); acc[3]=fmaf(nr,d,acc[3]);
    } else {
      unsigned int u = *(const unsigned int*)r;
      float a,b2; bf2x(u,a,b2);
      acc[0]=fmaf(nr,a,acc[0]); acc[1]=fmaf(nr,b2,acc[1]);
    }
  }
  float* o = out + (size_t)i*D + lane*V;
  if constexpr (V == 4){
    float4 st = make_float4(acc[0] + (BIAS?bias[lane*4+0]:0.f),
                            acc[1] + (BIAS?bias[lane*4+1]:0.f),
                            acc[2] + (BIAS?bias[lane*4+2]:0.f),
                            acc[3] + (BIAS?bias[lane*4+3]:0.f));
    *(float4*)o = st;
  } else {
    float2 st = make_float2(acc[0] + (BIAS?bias[lane*2+0]:0.f),
                            acc[1] + (BIAS?bias[lane*2+1]:0.f));
    *(float2*)o = st;
  }
}

// ---------------- BatchNorm stats (partials, fp64 accum) ----------------
__global__ void k_stats(const float* xc, double* part, int N){
  int ch = threadIdx.x;
  double s = 0, q = 0;
  for (int r = blockIdx.x; r < N; r += gridDim.x){
    float v = xc[(size_t)r*256 + ch];
    s += v; q += (double)v * v;
  }
  part[blockIdx.x*512 + ch]       = s;
  part[blockIdx.x*512 + 256 + ch] = q;
}

__global__ void k_bnfin(const double* part, const float* g, const float* b, float* ss, int N, int nb){
  int ch = threadIdx.x;
  double s = 0, q = 0;
  for (int i = 0; i < nb; i++){ s += part[i*512 + ch]; q += part[i*512 + 256 + ch]; }
  double mean = s / N;
  double var  = q / N - mean*mean;   // biased var, matches reference
  float sc = g[ch] * rsqrtf((float)var + EPSV);
  ss[ch]       = sc;
  ss[256 + ch] = b[ch] - (float)mean * sc;
}

// ---------------- BN apply + ReLU + residual (+ node_features on layer 0) ----------------
__global__ void k_apply(const float* xc, const float* ss, const float* resid,
                        const unsigned short* nf, float* outc, int total4){
  for (int idx = blockIdx.x*blockDim.x + threadIdx.x; idx < total4; idx += gridDim.x*blockDim.x){
    int cq = idx & 63;
    float4 v  = ((const float4*)xc)[idx];
    float4 sc = ((const float4*)ss)[cq];
    float4 sh = ((const float4*)ss)[64 + cq];
    float4 r  = ((const float4*)resid)[idx];
    float o0 = fmaxf(fmaf(v.x, sc.x, sh.x), 0.0f) + r.x;
    float o1 = fmaxf(fmaf(v.y, sc.y, sh.y), 0.0f) + r.y;
    float o2 = fmaxf(fmaf(v.z, sc.z, sh.z), 0.0f) + r.z;
    float o3 = fmaxf(fmaf(v.w, sc.w, sh.w), 0.0f) + r.w;
    if (nf){
      uint2 u = ((const uint2*)nf)[idx];
      float a,b2,c,d; bf2x(u.x,a,b2); bf2x(u.y,c,d);
      o0 += a; o1 += b2; o2 += c; o3 += d;
    }
    ((float4*)outc)[idx] = make_float4(o0, o1, o2, o3);
  }
}

// ---------------- global mean pool ----------------
__global__ void k_graph(const float* ne, float* g, int N){
  int c = threadIdx.x;   // 128
  int r0 = blockIdx.x * 512;
  int rmax = min(r0 + 512, N);
  float s = 0;
  for (int r = r0; r < rmax; r++) s += ne[(size_t)r*128 + c];
  atomicAdd(&g[c], s / (float)N);
}

extern "C" void kernel_launch(void* const* d_in, const int* in_sizes, int n_in,
                              void* d_out, int out_size, void* d_ws, size_t ws_size,
                              hipStream_t stream){
  const float* x     = (const float*)d_in[0];
  const int*   ei    = (const int*)d_in[1];     // harness passes integers as int32
  const float* ew    = (const float*)d_in[2];
  const float* W_nt1 = (const float*)d_in[3];
  const float* b_nt1 = (const float*)d_in[4];
  const float* W_nt2 = (const float*)d_in[5];
  const float* b_nt2 = (const float*)d_in[6];
  const float* ln_g  = (const float*)d_in[7];
  const float* ln_b  = (const float*)d_in[8];
  const float* Wc    = (const float*)d_in[9];
  // d_in[10] = bc (hidden conv bias): exactly cancelled by BN mean-subtraction — skipped
  const float* bn_g  = (const float*)d_in[11];
  const float* bn_b  = (const float*)d_in[12];
  const float* Wl    = (const float*)d_in[13];
  const float* bl    = (const float*)d_in[14];

  const int N = in_sizes[0] / 256;
  const int E = in_sizes[2];

  char* w = (char*)d_ws;
  size_t o = 0;
  auto alloc = [&](size_t bytes) -> void* {
    void* p = w + o;
    o = (o + bytes + 255) & ~(size_t)255;
    return p;
  };
  float* deg   = (float*)alloc((size_t)N*4);
  float* dis   = (float*)alloc((size_t)N*4);
  int*   cnt   = (int*)  alloc((size_t)N*4);   // reused as bucket cursor after scan
  int*   offs  = (int*)  alloc((size_t)(N+1)*4);
  int2*  ep    = (int2*) alloc((size_t)E*8);
  unsigned short* WT = (unsigned short*)alloc((size_t)6*65536*2);
  unsigned short* xw = (unsigned short*)alloc((size_t)N*256*2);  // also holds h1
  unsigned short* nf = (unsigned short*)alloc((size_t)N*256*2);
  float* xc   = (float*)alloc((size_t)N*256*4);                  // also holds h2
  float* cur  = (float*)alloc((size_t)N*256*4);
  double* part = (double*)alloc((size_t)256*512*8);
  float* ss   = (float*)alloc(512*4);

  float* node_emb  = (float*)d_out;
  float* graph_emb = node_emb + (size_t)N*128;

  const int gN = (N + 255)/256, gE = (E + 255)/256, gW = (N + 3)/4;

  hipMemsetAsync(graph_emb, 0, 128*sizeof(float), stream);
  k_init<<<gN, 256, 0, stream>>>(deg, cnt, N);
  k_deg <<<gE, 256, 0, stream>>>(ei, ew, deg, cnt, E);
  k_dis <<<gN, 256, 0, stream>>>(deg, dis, N);
  k_scan<<<1, 1024, 0, stream>>>(cnt, offs, N);
  k_zero<<<gN, 256, 0, stream>>>(cnt, N);
  k_bucket<<<gE, 256, 0, stream>>>(ei, ew, dis, offs, cnt, ep, E);
  k_wt  <<<256, 256, 0, stream>>>(W_nt1, W_nt2, Wc, Wl, WT);

  dim3 gg((N + 127)/128, 2);
  // node_transform: h1 = relu(x@W1+b1)  (bf16 out) ; h2 = h1@W2+b2 (fp32) ; LN -> nf (bf16)
  k_gemm<false, true,  true, true ><<<gg, 256, 0, stream>>>(x,  WT + 0*65536, b_nt1, xw, N, 256);
  k_gemm<true,  false, true, false><<<gg, 256, 0, stream>>>(xw, WT + 1*65536, b_nt2, xc, N, 256);
  k_ln<<<gW, 256, 0, stream>>>(xc, ln_g, ln_b, nf, N);

  for (int i = 0; i < 3; i++){
    const float* cin = (i == 0) ? x : cur;
    k_gemm<false, true, false, false><<<gg, 256, 0, stream>>>(cin, WT + (size_t)(2+i)*65536, nullptr, xw, N, 256);
    k_agg<256, false><<<gW, 256, 0, stream>>>(xw, ep, offs, dis, nullptr, xc, N);
    k_stats<<<256, 256, 0, stream>>>(xc, part, N);
    k_bnfin<<<1, 256, 0, stream>>>(part, bn_g + i*256, bn_b + i*256, ss, N, 256);
    k_apply<<<2048, 256, 0, stream>>>(xc, ss, cin, (i == 0) ? nf : nullptr, cur, N*64);
  }

  dim3 gl((N + 127)/128, 1);
  k_gemm<false, true, false, false><<<gl, 256, 0, stream>>>(cur, WT + (size_t)5*65536, nullptr, xw, N, 128);
  k_agg<128, true><<<gW, 256, 0, stream>>>(xw, ep, offs, dis, bl, node_emb, N);
  k_graph<<<(N + 511)/512, 128, 0, stream>>>(node_emb, graph_emb, N);
}

// Round 3
// 1000.849 us; speedup vs baseline: 1.3965x; 1.3965x over previous
//
#include <hip/hip_runtime.h>

#define EPSV 1e-5f

typedef __attribute__((ext_vector_type(8))) short v8s;
typedef __attribute__((ext_vector_type(4))) float v4f;

__device__ __forceinline__ unsigned short f2bf(float f){
  unsigned int u = __float_as_uint(f);
  u += 0x7FFF + ((u >> 16) & 1);
  return (unsigned short)(u >> 16);
}
__device__ __forceinline__ void bf2x(unsigned int u, float& lo, float& hi){
  lo = __uint_as_float(u << 16);
  hi = __uint_as_float(u & 0xffff0000u);
}

// ---------------- preprocessing ----------------
// NOTE: harness passes integer inputs as int32 (edge_index is [2,E] int32 here).
__global__ void k_init(float* deg, int* cnt, int N){
  int i = blockIdx.x*256 + threadIdx.x;
  if (i < N){ deg[i] = 1.0f; cnt[i] = 0; }   // deg=1: self-loop weight
}

__global__ void k_deg(const int* ei, const float* ew, float* deg, int* cnt, int E){
  int e = blockIdx.x*256 + threadIdx.x;
  if (e < E){
    int c = ei[E + e];
    atomicAdd(&deg[c], ew[e]);
    atomicAdd(&cnt[c], 1);
  }
}

__global__ void k_dis(const float* deg, float* dis, int N){
  int i = blockIdx.x*256 + threadIdx.x;
  if (i < N) dis[i] = rsqrtf(deg[i]);   // deg >= 1 always
}

__global__ void k_scan(const int* cnt, int* offs, int N){
  __shared__ int sm[1024];
  int t = threadIdx.x;
  int C = (N + 1023) >> 10;
  int base = t * C;
  int s = 0;
  for (int j = 0; j < C; j++){ int idx = base + j; if (idx < N) s += cnt[idx]; }
  sm[t] = s;
  __syncthreads();
  for (int off = 1; off < 1024; off <<= 1){
    int v = (t >= off) ? sm[t - off] : 0;
    __syncthreads();
    sm[t] += v;
    __syncthreads();
  }
  int run = sm[t] - s;   // exclusive prefix
  for (int j = 0; j < C; j++){
    int idx = base + j;
    if (idx <= N){
      offs[idx] = run;
      if (idx < N) run += cnt[idx];
    }
  }
}

// cnt is reused as the per-node cursor (zeroed by k_zero before this runs)
__global__ void k_bucket(const int* ei, const float* ew, const float* dis, const int* offs,
                         int* cursor, int2* ep, int E){
  int e = blockIdx.x*256 + threadIdx.x;
  if (e < E){
    int r = ei[e], c = ei[E + e];
    float nrm = dis[r] * ew[e] * dis[c];
    int pos = offs[c] + atomicAdd(&cursor[c], 1);
    ep[pos] = make_int2(r, __float_as_int(nrm));
  }
}

__global__ void k_zero(int* p, int N){
  int i = blockIdx.x*256 + threadIdx.x;
  if (i < N) p[i] = 0;
}

// transpose + bf16-convert all weights: [WT1|WT2|WTc0|WTc1|WTc2|WTlast], each [n][k], k-stride 256
__global__ void k_wt(const float* W1, const float* W2, const float* Wc, const float* Wl,
                     unsigned short* WT){
  int t = blockIdx.x*256 + threadIdx.x;   // 65536 threads
  int k = t >> 8, n = t & 255;
  WT[0*65536 + n*256 + k] = f2bf(W1[k*256 + n]);
  WT[1*65536 + n*256 + k] = f2bf(W2[k*256 + n]);
  WT[2*65536 + n*256 + k] = f2bf(Wc[0*65536 + k*256 + n]);
  WT[3*65536 + n*256 + k] = f2bf(Wc[1*65536 + k*256 + n]);
  WT[4*65536 + n*256 + k] = f2bf(Wc[2*65536 + k*256 + n]);
  if (n < 128) WT[5*65536 + n*256 + k] = f2bf(Wl[k*128 + n]);
}

// ---------------- bf16 MFMA GEMM: C[M,Nout] = A[M,256] * W[256,Nout], WT passed as [Nout][256] ----------------
template<bool ABF16, bool OUTBF16, bool BIAS, bool RELU>
__global__ __launch_bounds__(256, 2) void k_gemm(const void* Ap, const unsigned short* WT,
    const float* bias, void* Cp, int M, int Nout){
  __shared__ unsigned short As[128][40];
  __shared__ unsigned short Bs[128][40];
  const int tid  = threadIdx.x;
  const int lane = tid & 63, wv = tid >> 6;
  const int wm = wv >> 1, wn = wv & 1;
  const int quad = lane >> 4, m16 = lane & 15;
  const int bm = blockIdx.x, bn = blockIdx.y;
  const int srow = tid >> 1, sseg = (tid & 1) * 16;
  const int arow_g = min(bm*128 + srow, M - 1);

  v4f acc[4][4];
  #pragma unroll
  for (int a = 0; a < 4; a++)
    #pragma unroll
    for (int b = 0; b < 4; b++) acc[a][b] = (v4f)(0.0f);

  const float* Af = (const float*)Ap;
  const unsigned short* Ab = (const unsigned short*)Ap;

  for (int ks = 0; ks < 256; ks += 32){
    __syncthreads();
    if constexpr (ABF16){
      const unsigned short* src = Ab + (size_t)arow_g*256 + ks + sseg;
      uint4 u0 = *(const uint4*)(src);
      uint4 u1 = *(const uint4*)(src + 8);
      *(uint4*)&As[srow][sseg]     = u0;
      *(uint4*)&As[srow][sseg + 8] = u1;
    } else {
      const float* src = Af + (size_t)arow_g*256 + ks + sseg;
      float4 v0 = *(const float4*)(src + 0);
      float4 v1 = *(const float4*)(src + 4);
      float4 v2 = *(const float4*)(src + 8);
      float4 v3 = *(const float4*)(src + 12);
      uint4 q0, q1;
      q0.x = f2bf(v0.x) | ((unsigned)f2bf(v0.y) << 16);
      q0.y = f2bf(v0.z) | ((unsigned)f2bf(v0.w) << 16);
      q0.z = f2bf(v1.x) | ((unsigned)f2bf(v1.y) << 16);
      q0.w = f2bf(v1.z) | ((unsigned)f2bf(v1.w) << 16);
      q1.x = f2bf(v2.x) | ((unsigned)f2bf(v2.y) << 16);
      q1.y = f2bf(v2.z) | ((unsigned)f2bf(v2.w) << 16);
      q1.z = f2bf(v3.x) | ((unsigned)f2bf(v3.y) << 16);
      q1.w = f2bf(v3.z) | ((unsigned)f2bf(v3.w) << 16);
      *(uint4*)&As[srow][sseg]     = q0;
      *(uint4*)&As[srow][sseg + 8] = q1;
    }
    {
      const unsigned short* src = WT + (size_t)(bn*128 + srow)*256 + ks + sseg;
      uint4 u0 = *(const uint4*)(src);
      uint4 u1 = *(const uint4*)(src + 8);
      *(uint4*)&Bs[srow][sseg]     = u0;
      *(uint4*)&Bs[srow][sseg + 8] = u1;
    }
    __syncthreads();

    v8s af[4], bfr[4];
    #pragma unroll
    for (int tm = 0; tm < 4; tm++) af[tm]  = *(const v8s*)&As[wm*64 + tm*16 + m16][quad*8];
    #pragma unroll
    for (int tn = 0; tn < 4; tn++) bfr[tn] = *(const v8s*)&Bs[wn*64 + tn*16 + m16][quad*8];
    #pragma unroll
    for (int tm = 0; tm < 4; tm++)
      #pragma unroll
      for (int tn = 0; tn < 4; tn++)
        acc[tm][tn] = __builtin_amdgcn_mfma_f32_16x16x32_bf16(af[tm], bfr[tn], acc[tm][tn], 0, 0, 0);
  }

  #pragma unroll
  for (int tn = 0; tn < 4; tn++){
    int col = bn*128 + wn*64 + tn*16 + m16;
    float bv = BIAS ? bias[col] : 0.0f;
    #pragma unroll
    for (int tm = 0; tm < 4; tm++){
      int row0 = bm*128 + wm*64 + tm*16 + quad*4;
      #pragma unroll
      for (int r = 0; r < 4; r++){
        int row = row0 + r;
        if (row < M){
          float v = acc[tm][tn][r] + bv;
          if (RELU) v = fmaxf(v, 0.0f);
          if (OUTBF16) ((unsigned short*)Cp)[(size_t)row*Nout + col] = f2bf(v);
          else         ((float*)Cp)[(size_t)row*Nout + col] = v;
        }
      }
    }
  }
}

// ---------------- LayerNorm (one wave per node) ----------------
__global__ __launch_bounds__(256) void k_ln(const float* h, const float* g, const float* b,
                                            unsigned short* nf, int N){
  const int lane = threadIdx.x & 63, wv = threadIdx.x >> 6;
  const int i = blockIdx.x*4 + wv;
  if (i >= N) return;
  const float* row = h + (size_t)i*256;
  float4 v = *(const float4*)(row + lane*4);
  float s = v.x + v.y + v.z + v.w;
  float q = v.x*v.x + v.y*v.y + v.z*v.z + v.w*v.w;
  for (int off = 32; off > 0; off >>= 1){
    s += __shfl_xor(s, off, 64);
    q += __shfl_xor(q, off, 64);
  }
  float mean = s * (1.0f/256.0f);
  float var  = q * (1.0f/256.0f) - mean*mean;
  float rs = rsqrtf(var + EPSV);
  int c = lane*4;
  ushort4 st;
  st.x = f2bf((v.x - mean)*rs*g[c+0] + b[c+0]);
  st.y = f2bf((v.y - mean)*rs*g[c+1] + b[c+1]);
  st.z = f2bf((v.z - mean)*rs*g[c+2] + b[c+2]);
  st.w = f2bf((v.w - mean)*rs*g[c+3] + b[c+3]);
  *(ushort4*)(nf + (size_t)i*256 + c) = st;
}

// ---------------- CSR aggregation: one wave per destination node ----------------
// Edges batched 64-wide per wave: one coalesced ep load, __shfl broadcast,
// 4-wide unrolled gathers for memory-level parallelism.
template<int D, bool BIAS>
__global__ __launch_bounds__(256) void k_agg(const unsigned short* xw, const int2* ep,
    const int* offs, const float* dis, const float* bias, float* out, int N){
  constexpr int V = D / 64;
  const int lane = threadIdx.x & 63, wv = threadIdx.x >> 6;
  const int i = blockIdx.x*4 + wv;
  if (i >= N) return;
  float acc[V];
  float dsi = dis[i];
  float coef = dsi * dsi;   // self-loop norm
  {
    const unsigned short* r = xw + (size_t)i*D + lane*V;
    if constexpr (V == 4){
      uint2 u = *(const uint2*)r;
      float a,b2,c,d; bf2x(u.x,a,b2); bf2x(u.y,c,d);
      acc[0]=coef*a; acc[1]=coef*b2; acc[2]=coef*c; acc[3]=coef*d;
    } else {
      unsigned int u = *(const unsigned int*)r;
      float a,b2; bf2x(u,a,b2);
      acc[0]=coef*a; acc[1]=coef*b2;
    }
  }
  const int e0 = offs[i], e1 = offs[i+1];
  for (int eb = e0; eb < e1; eb += 64){
    const int nb = min(64, e1 - eb);
    int2 pl = make_int2(0, 0);
    if (eb + lane < e1) pl = ep[eb + lane];
    int j = 0;
    for (; j + 4 <= nb; j += 4){
      int   s0 = __shfl(pl.x, j+0, 64), s1 = __shfl(pl.x, j+1, 64);
      int   s2 = __shfl(pl.x, j+2, 64), s3 = __shfl(pl.x, j+3, 64);
      float n0 = __int_as_float(__shfl(pl.y, j+0, 64));
      float n1 = __int_as_float(__shfl(pl.y, j+1, 64));
      float n2 = __int_as_float(__shfl(pl.y, j+2, 64));
      float n3 = __int_as_float(__shfl(pl.y, j+3, 64));
      if constexpr (V == 4){
        uint2 u0 = *(const uint2*)(xw + (size_t)s0*D + lane*V);
        uint2 u1 = *(const uint2*)(xw + (size_t)s1*D + lane*V);
        uint2 u2 = *(const uint2*)(xw + (size_t)s2*D + lane*V);
        uint2 u3 = *(const uint2*)(xw + (size_t)s3*D + lane*V);
        float a,b2,c,d;
        bf2x(u0.x,a,b2); bf2x(u0.y,c,d);
        acc[0]=fmaf(n0,a,acc[0]); acc[1]=fmaf(n0,b2,acc[1]); acc[2]=fmaf(n0,c,acc[2]); acc[3]=fmaf(n0,d,acc[3]);
        bf2x(u1.x,a,b2); bf2x(u1.y,c,d);
        acc[0]=fmaf(n1,a,acc[0]); acc[1]=fmaf(n1,b2,acc[1]); acc[2]=fmaf(n1,c,acc[2]); acc[3]=fmaf(n1,d,acc[3]);
        bf2x(u2.x,a,b2); bf2x(u2.y,c,d);
        acc[0]=fmaf(n2,a,acc[0]); acc[1]=fmaf(n2,b2,acc[1]); acc[2]=fmaf(n2,c,acc[2]); acc[3]=fmaf(n2,d,acc[3]);
        bf2x(u3.x,a,b2); bf2x(u3.y,c,d);
        acc[0]=fmaf(n3,a,acc[0]); acc[1]=fmaf(n3,b2,acc[1]); acc[2]=fmaf(n3,c,acc[2]); acc[3]=fmaf(n3,d,acc[3]);
      } else {
        unsigned int u0 = *(const unsigned int*)(xw + (size_t)s0*D + lane*V);
        unsigned int u1 = *(const unsigned int*)(xw + (size_t)s1*D + lane*V);
        unsigned int u2 = *(const unsigned int*)(xw + (size_t)s2*D + lane*V);
        unsigned int u3 = *(const unsigned int*)(xw + (size_t)s3*D + lane*V);
        float a,b2;
        bf2x(u0,a,b2); acc[0]=fmaf(n0,a,acc[0]); acc[1]=fmaf(n0,b2,acc[1]);
        bf2x(u1,a,b2); acc[0]=fmaf(n1,a,acc[0]); acc[1]=fmaf(n1,b2,acc[1]);
        bf2x(u2,a,b2); acc[0]=fmaf(n2,a,acc[0]); acc[1]=fmaf(n2,b2,acc[1]);
        bf2x(u3,a,b2); acc[0]=fmaf(n3,a,acc[0]); acc[1]=fmaf(n3,b2,acc[1]);
      }
    }
    for (; j < nb; j++){
      int   s0 = __shfl(pl.x, j, 64);
      float n0 = __int_as_float(__shfl(pl.y, j, 64));
      if constexpr (V == 4){
        uint2 u = *(const uint2*)(xw + (size_t)s0*D + lane*V);
        float a,b2,c,d; bf2x(u.x,a,b2); bf2x(u.y,c,d);
        acc[0]=fmaf(n0,a,acc[0]); acc[1]=fmaf(n0,b2,acc[1]);
        acc[2]=fmaf(n0,c,acc[2]); acc[3]=fmaf(n0,d,acc[3]);
      } else {
        unsigned int u = *(const unsigned int*)(xw + (size_t)s0*D + lane*V);
        float a,b2; bf2x(u,a,b2);
        acc[0]=fmaf(n0,a,acc[0]); acc[1]=fmaf(n0,b2,acc[1]);
      }
    }
  }
  float* o = out + (size_t)i*D + lane*V;
  if constexpr (V == 4){
    float4 st = make_float4(acc[0] + (BIAS?bias[lane*4+0]:0.f),
                            acc[1] + (BIAS?bias[lane*4+1]:0.f),
                            acc[2] + (BIAS?bias[lane*4+2]:0.f),
                            acc[3] + (BIAS?bias[lane*4+3]:0.f));
    *(float4*)o = st;
  } else {
    float2 st = make_float2(acc[0] + (BIAS?bias[lane*2+0]:0.f),
                            acc[1] + (BIAS?bias[lane*2+1]:0.f));
    *(float2*)o = st;
  }
}

// ---------------- BatchNorm stats: 512 blocks, float4 loads, atomic fp32 partials ----------------
__global__ __launch_bounds__(256) void k_stats(const float* xc, float* acc, int N){
  const int t  = threadIdx.x;
  const int c4 = t & 63;        // which float4 of the 256 channels
  const int rs = t >> 6;        // 0..3 row slice
  const int rows = (N + gridDim.x - 1) / gridDim.x;
  const int r0 = blockIdx.x * rows;
  const int r1 = min(r0 + rows, N);
  float4 s = make_float4(0,0,0,0), q = make_float4(0,0,0,0);
  for (int r = r0 + rs; r < r1; r += 4){
    float4 v = ((const float4*)(xc + (size_t)r*256))[c4];
    s.x += v.x; s.y += v.y; s.z += v.z; s.w += v.w;
    q.x = fmaf(v.x, v.x, q.x); q.y = fmaf(v.y, v.y, q.y);
    q.z = fmaf(v.z, v.z, q.z); q.w = fmaf(v.w, v.w, q.w);
  }
  __shared__ float4 sm[512];
  sm[t] = s; sm[256 + t] = q;
  __syncthreads();
  for (int off = 128; off >= 64; off >>= 1){
    if (t < off){
      float4 a = sm[t + off];       sm[t].x += a.x; sm[t].y += a.y; sm[t].z += a.z; sm[t].w += a.w;
      float4 b = sm[256 + t + off]; sm[256+t].x += b.x; sm[256+t].y += b.y; sm[256+t].z += b.z; sm[256+t].w += b.w;
    }
    __syncthreads();
  }
  if (t < 64){
    float4 sv = sm[t], qv = sm[256 + t];
    atomicAdd(&acc[t*4+0], sv.x); atomicAdd(&acc[t*4+1], sv.y);
    atomicAdd(&acc[t*4+2], sv.z); atomicAdd(&acc[t*4+3], sv.w);
    atomicAdd(&acc[256+t*4+0], qv.x); atomicAdd(&acc[256+t*4+1], qv.y);
    atomicAdd(&acc[256+t*4+2], qv.z); atomicAdd(&acc[256+t*4+3], qv.w);
  }
}

__global__ void k_bnfin(const float* acc, const float* g, const float* b, float* ss, int N){
  int ch = threadIdx.x;
  float mean = acc[ch] / (float)N;
  float var  = acc[256 + ch] / (float)N - mean*mean;   // biased var, matches reference
  float sc = g[ch] * rsqrtf(var + EPSV);
  ss[ch]       = sc;
  ss[256 + ch] = b[ch] - mean * sc;
}

// ---------------- BN apply + ReLU + residual (+ node_features on layer 0) ----------------
__global__ void k_apply(const float* xc, const float* ss, const float* resid,
                        const unsigned short* nf, float* outc, int total4){
  for (int idx = blockIdx.x*blockDim.x + threadIdx.x; idx < total4; idx += gridDim.x*blockDim.x){
    int cq = idx & 63;
    float4 v  = ((const float4*)xc)[idx];
    float4 sc = ((const float4*)ss)[cq];
    float4 sh = ((const float4*)ss)[64 + cq];
    float4 r  = ((const float4*)resid)[idx];
    float o0 = fmaxf(fmaf(v.x, sc.x, sh.x), 0.0f) + r.x;
    float o1 = fmaxf(fmaf(v.y, sc.y, sh.y), 0.0f) + r.y;
    float o2 = fmaxf(fmaf(v.z, sc.z, sh.z), 0.0f) + r.z;
    float o3 = fmaxf(fmaf(v.w, sc.w, sh.w), 0.0f) + r.w;
    if (nf){
      uint2 u = ((const uint2*)nf)[idx];
      float a,b2,c,d; bf2x(u.x,a,b2); bf2x(u.y,c,d);
      o0 += a; o1 += b2; o2 += c; o3 += d;
    }
    ((float4*)outc)[idx] = make_float4(o0, o1, o2, o3);
  }
}

// ---------------- global mean pool: 256 blocks, float4, LDS tree, atomic tail ----------------
__global__ __launch_bounds__(256) void k_graph(const float* ne, float* g, int N){
  const int t  = threadIdx.x;
  const int c4 = t & 31;        // which float4 of the 128 channels
  const int rs = t >> 5;        // 0..7 row slice
  const int rows = (N + gridDim.x - 1) / gridDim.x;
  const int r0 = blockIdx.x * rows;
  const int r1 = min(r0 + rows, N);
  float4 a = make_float4(0,0,0,0);
  for (int r = r0 + rs; r < r1; r += 8){
    float4 v = ((const float4*)(ne + (size_t)r*128))[c4];
    a.x += v.x; a.y += v.y; a.z += v.z; a.w += v.w;
  }
  __shared__ float4 sm[256];
  sm[t] = a;
  __syncthreads();
  for (int off = 128; off >= 32; off >>= 1){
    if (t < off){
      float4 b = sm[t + off];
      sm[t].x += b.x; sm[t].y += b.y; sm[t].z += b.z; sm[t].w += b.w;
    }
    __syncthreads();
  }
  if (t < 32){
    float4 v = sm[t];
    float inv = 1.0f / (float)N;
    atomicAdd(&g[t*4+0], v.x*inv); atomicAdd(&g[t*4+1], v.y*inv);
    atomicAdd(&g[t*4+2], v.z*inv); atomicAdd(&g[t*4+3], v.w*inv);
  }
}

extern "C" void kernel_launch(void* const* d_in, const int* in_sizes, int n_in,
                              void* d_out, int out_size, void* d_ws, size_t ws_size,
                              hipStream_t stream){
  const float* x     = (const float*)d_in[0];
  const int*   ei    = (const int*)d_in[1];     // harness passes integers as int32
  const float* ew    = (const float*)d_in[2];
  const float* W_nt1 = (const float*)d_in[3];
  const float* b_nt1 = (const float*)d_in[4];
  const float* W_nt2 = (const float*)d_in[5];
  const float* b_nt2 = (const float*)d_in[6];
  const float* ln_g  = (const float*)d_in[7];
  const float* ln_b  = (const float*)d_in[8];
  const float* Wc    = (const float*)d_in[9];
  // d_in[10] = bc (hidden conv bias): exactly cancelled by BN mean-subtraction — skipped
  const float* bn_g  = (const float*)d_in[11];
  const float* bn_b  = (const float*)d_in[12];
  const float* Wl    = (const float*)d_in[13];
  const float* bl    = (const float*)d_in[14];

  const int N = in_sizes[0] / 256;
  const int E = in_sizes[2];

  char* w = (char*)d_ws;
  size_t o = 0;
  auto alloc = [&](size_t bytes) -> void* {
    void* p = w + o;
    o = (o + bytes + 255) & ~(size_t)255;
    return p;
  };
  float* deg   = (float*)alloc((size_t)N*4);
  float* dis   = (float*)alloc((size_t)N*4);
  int*   cnt   = (int*)  alloc((size_t)N*4);   // reused as bucket cursor after scan
  int*   offs  = (int*)  alloc((size_t)(N+1)*4);
  int2*  ep    = (int2*) alloc((size_t)E*8);
  unsigned short* WT = (unsigned short*)alloc((size_t)6*65536*2);
  unsigned short* xw = (unsigned short*)alloc((size_t)N*256*2);  // also holds h1
  unsigned short* nf = (unsigned short*)alloc((size_t)N*256*2);
  float* xc   = (float*)alloc((size_t)N*256*4);                  // also holds h2
  float* cur  = (float*)alloc((size_t)N*256*4);
  float* bnacc = (float*)alloc(512*4);
  float* ss   = (float*)alloc(512*4);

  float* node_emb  = (float*)d_out;
  float* graph_emb = node_emb + (size_t)N*128;

  const int gN = (N + 255)/256, gE = (E + 255)/256, gW = (N + 3)/4;

  hipMemsetAsync(graph_emb, 0, 128*sizeof(float), stream);
  k_init<<<gN, 256, 0, stream>>>(deg, cnt, N);
  k_deg <<<gE, 256, 0, stream>>>(ei, ew, deg, cnt, E);
  k_dis <<<gN, 256, 0, stream>>>(deg, dis, N);
  k_scan<<<1, 1024, 0, stream>>>(cnt, offs, N);
  k_zero<<<gN, 256, 0, stream>>>(cnt, N);
  k_bucket<<<gE, 256, 0, stream>>>(ei, ew, dis, offs, cnt, ep, E);
  k_wt  <<<256, 256, 0, stream>>>(W_nt1, W_nt2, Wc, Wl, WT);

  dim3 gg((N + 127)/128, 2);
  // node_transform: h1 = relu(x@W1+b1)  (bf16 out) ; h2 = h1@W2+b2 (fp32) ; LN -> nf (bf16)
  k_gemm<false, true,  true, true ><<<gg, 256, 0, stream>>>(x,  WT + 0*65536, b_nt1, xw, N, 256);
  k_gemm<true,  false, true, false><<<gg, 256, 0, stream>>>(xw, WT + 1*65536, b_nt2, xc, N, 256);
  k_ln<<<gW, 256, 0, stream>>>(xc, ln_g, ln_b, nf, N);

  for (int i = 0; i < 3; i++){
    const float* cin = (i == 0) ? x : cur;
    k_gemm<false, true, false, false><<<gg, 256, 0, stream>>>(cin, WT + (size_t)(2+i)*65536, nullptr, xw, N, 256);
    k_agg<256, false><<<gW, 256, 0, stream>>>(xw, ep, offs, dis, nullptr, xc, N);
    hipMemsetAsync(bnacc, 0, 512*sizeof(float), stream);
    k_stats<<<512, 256, 0, stream>>>(xc, bnacc, N);
    k_bnfin<<<1, 256, 0, stream>>>(bnacc, bn_g + i*256, bn_b + i*256, ss, N);
    k_apply<<<2048, 256, 0, stream>>>(xc, ss, cin, (i == 0) ? nf : nullptr, cur, N*64);
  }

  dim3 gl((N + 127)/128, 1);
  k_gemm<false, true, false, false><<<gl, 256, 0, stream>>>(cur, WT + (size_t)5*65536, nullptr, xw, N, 128);
  k_agg<128, true><<<gW, 256, 0, stream>>>(xw, ep, offs, dis, bl, node_emb, N);
  k_graph<<<256, 256, 0, stream>>>(node_emb, graph_emb, N);
}

// Round 4
// 916.013 us; speedup vs baseline: 1.5258x; 1.0926x over previous
//
#include <hip/hip_runtime.h>

#define EPSV 1e-5f

typedef __attribute__((ext_vector_type(8))) short v8s;
typedef __attribute__((ext_vector_type(4))) float v4f;

__device__ __forceinline__ unsigned short f2bf(float f){
  unsigned int u = __float_as_uint(f);
  u += 0x7FFF + ((u >> 16) & 1);
  return (unsigned short)(u >> 16);
}
__device__ __forceinline__ void bf2x(unsigned int u, float& lo, float& hi){
  lo = __uint_as_float(u << 16);
  hi = __uint_as_float(u & 0xffff0000u);
}

// ---------------- preprocessing ----------------
// NOTE: harness passes integer inputs as int32 (edge_index is [2,E] int32 here).
__global__ void k_init(float* deg, int* cnt, int N){
  int i = blockIdx.x*256 + threadIdx.x;
  if (i < N){ deg[i] = 1.0f; cnt[i] = 0; }   // deg=1: self-loop weight
}

__global__ void k_deg(const int* ei, const float* ew, float* deg, int* cnt, int E){
  int e = blockIdx.x*256 + threadIdx.x;
  if (e < E){
    int c = ei[E + e];
    atomicAdd(&deg[c], ew[e]);
    atomicAdd(&cnt[c], 1);
  }
}

__global__ void k_dis(const float* deg, float* dis, int N){
  int i = blockIdx.x*256 + threadIdx.x;
  if (i < N) dis[i] = rsqrtf(deg[i]);   // deg >= 1 always
}

// ---------------- 3-phase coalesced exclusive scan over cnt[N] -> offs[N+1] ----------------
// phase 1: per-block (1024 elems) sums
__global__ __launch_bounds__(256) void k_scan1(const int* cnt, int* part, int N){
  const int t = threadIdx.x, b = blockIdx.x;
  const int base = b*1024 + t*4;
  int4 v = make_int4(0,0,0,0);
  if (base + 3 < N) v = *(const int4*)(cnt + base);
  else {
    if (base   < N) v.x = cnt[base];
    if (base+1 < N) v.y = cnt[base+1];
    if (base+2 < N) v.z = cnt[base+2];
    if (base+3 < N) v.w = cnt[base+3];
  }
  int s = v.x + v.y + v.z + v.w;
  __shared__ int sm[256];
  sm[t] = s;
  __syncthreads();
  for (int off = 128; off > 0; off >>= 1){
    if (t < off) sm[t] += sm[t + off];
    __syncthreads();
  }
  if (t == 0) part[b] = sm[0];
}

// phase 2: one wave scans block sums (NB <= 64), writes exclusive part + total -> offs[N]
__global__ __launch_bounds__(64) void k_scan2(int* part, int* offs, int NB, int N){
  const int t = threadIdx.x;
  int orig = (t < NB) ? part[t] : 0;
  int v = orig;
  for (int off = 1; off < 64; off <<= 1){
    int u = __shfl_up(v, off, 64);
    if (t >= off) v += u;
  }
  if (t < NB) part[t] = v - orig;   // exclusive block prefix
  if (t == 63) offs[N] = v;         // grand total = E
}

// phase 3: recompute local prefix, add block offset, write offs; zero cnt (cursor reuse)
__global__ __launch_bounds__(256) void k_scan3(int* cnt, const int* part, int* offs, int N){
  const int t = threadIdx.x, b = blockIdx.x;
  const int base = b*1024 + t*4;
  int4 v = make_int4(0,0,0,0);
  if (base + 3 < N) v = *(const int4*)(cnt + base);
  else {
    if (base   < N) v.x = cnt[base];
    if (base+1 < N) v.y = cnt[base+1];
    if (base+2 < N) v.z = cnt[base+2];
    if (base+3 < N) v.w = cnt[base+3];
  }
  int s = v.x + v.y + v.z + v.w;
  __shared__ int sm[256];
  sm[t] = s;
  __syncthreads();
  for (int off = 1; off < 256; off <<= 1){
    int u = (t >= off) ? sm[t - off] : 0;
    __syncthreads();
    sm[t] += u;
    __syncthreads();
  }
  int run = part[b] + sm[t] - s;    // global exclusive prefix for this thread's chunk
  if (base   < N) offs[base]   = run; run += v.x;
  if (base+1 < N) offs[base+1] = run; run += v.y;
  if (base+2 < N) offs[base+2] = run; run += v.z;
  if (base+3 < N) offs[base+3] = run;
  // zero the cursor for k_bucket (each element touched by exactly one thread)
  if (base + 3 < N) *(int4*)(cnt + base) = make_int4(0,0,0,0);
  else {
    if (base   < N) cnt[base]   = 0;
    if (base+1 < N) cnt[base+1] = 0;
    if (base+2 < N) cnt[base+2] = 0;
  }
}

// cnt is reused as the per-node cursor (zeroed by k_scan3)
__global__ void k_bucket(const int* ei, const float* ew, const float* dis, const int* offs,
                         int* cursor, int2* ep, int E){
  int e = blockIdx.x*256 + threadIdx.x;
  if (e < E){
    int r = ei[e], c = ei[E + e];
    float nrm = dis[r] * ew[e] * dis[c];
    int pos = offs[c] + atomicAdd(&cursor[c], 1);
    ep[pos] = make_int2(r, __float_as_int(nrm));
  }
}

// transpose + bf16-convert all weights: [WT1|WT2|WTc0|WTc1|WTc2|WTlast], each [n][k], k-stride 256
__global__ void k_wt(const float* W1, const float* W2, const float* Wc, const float* Wl,
                     unsigned short* WT){
  int t = blockIdx.x*256 + threadIdx.x;   // 65536 threads
  int k = t >> 8, n = t & 255;
  WT[0*65536 + n*256 + k] = f2bf(W1[k*256 + n]);
  WT[1*65536 + n*256 + k] = f2bf(W2[k*256 + n]);
  WT[2*65536 + n*256 + k] = f2bf(Wc[0*65536 + k*256 + n]);
  WT[3*65536 + n*256 + k] = f2bf(Wc[1*65536 + k*256 + n]);
  WT[4*65536 + n*256 + k] = f2bf(Wc[2*65536 + k*256 + n]);
  if (n < 128) WT[5*65536 + n*256 + k] = f2bf(Wl[k*128 + n]);
}

// ---------------- bf16 MFMA GEMM: C[M,Nout] = A[M,256] * W[256,Nout], WT passed as [Nout][256] ----------------
template<bool ABF16, bool OUTBF16, bool BIAS, bool RELU>
__global__ __launch_bounds__(256, 3) void k_gemm(const void* Ap, const unsigned short* WT,
    const float* bias, void* Cp, int M, int Nout){
  __shared__ unsigned short As[128][40];
  __shared__ unsigned short Bs[128][40];
  const int tid  = threadIdx.x;
  const int lane = tid & 63, wv = tid >> 6;
  const int wm = wv >> 1, wn = wv & 1;
  const int quad = lane >> 4, m16 = lane & 15;
  const int bm = blockIdx.x, bn = blockIdx.y;
  const int srow = tid >> 1, sseg = (tid & 1) * 16;
  const int arow_g = min(bm*128 + srow, M - 1);

  v4f acc[4][4];
  #pragma unroll
  for (int a = 0; a < 4; a++)
    #pragma unroll
    for (int b = 0; b < 4; b++) acc[a][b] = (v4f)(0.0f);

  const float* Af = (const float*)Ap;
  const unsigned short* Ab = (const unsigned short*)Ap;

  for (int ks = 0; ks < 256; ks += 32){
    __syncthreads();
    if constexpr (ABF16){
      const unsigned short* src = Ab + (size_t)arow_g*256 + ks + sseg;
      uint4 u0 = *(const uint4*)(src);
      uint4 u1 = *(const uint4*)(src + 8);
      *(uint4*)&As[srow][sseg]     = u0;
      *(uint4*)&As[srow][sseg + 8] = u1;
    } else {
      const float* src = Af + (size_t)arow_g*256 + ks + sseg;
      float4 v0 = *(const float4*)(src + 0);
      float4 v1 = *(const float4*)(src + 4);
      float4 v2 = *(const float4*)(src + 8);
      float4 v3 = *(const float4*)(src + 12);
      uint4 q0, q1;
      q0.x = f2bf(v0.x) | ((unsigned)f2bf(v0.y) << 16);
      q0.y = f2bf(v0.z) | ((unsigned)f2bf(v0.w) << 16);
      q0.z = f2bf(v1.x) | ((unsigned)f2bf(v1.y) << 16);
      q0.w = f2bf(v1.z) | ((unsigned)f2bf(v1.w) << 16);
      q1.x = f2bf(v2.x) | ((unsigned)f2bf(v2.y) << 16);
      q1.y = f2bf(v2.z) | ((unsigned)f2bf(v2.w) << 16);
      q1.z = f2bf(v3.x) | ((unsigned)f2bf(v3.y) << 16);
      q1.w = f2bf(v3.z) | ((unsigned)f2bf(v3.w) << 16);
      *(uint4*)&As[srow][sseg]     = q0;
      *(uint4*)&As[srow][sseg + 8] = q1;
    }
    {
      const unsigned short* src = WT + (size_t)(bn*128 + srow)*256 + ks + sseg;
      uint4 u0 = *(const uint4*)(src);
      uint4 u1 = *(const uint4*)(src + 8);
      *(uint4*)&Bs[srow][sseg]     = u0;
      *(uint4*)&Bs[srow][sseg + 8] = u1;
    }
    __syncthreads();

    v8s af[4], bfr[4];
    #pragma unroll
    for (int tm = 0; tm < 4; tm++) af[tm]  = *(const v8s*)&As[wm*64 + tm*16 + m16][quad*8];
    #pragma unroll
    for (int tn = 0; tn < 4; tn++) bfr[tn] = *(const v8s*)&Bs[wn*64 + tn*16 + m16][quad*8];
    #pragma unroll
    for (int tm = 0; tm < 4; tm++)
      #pragma unroll
      for (int tn = 0; tn < 4; tn++)
        acc[tm][tn] = __builtin_amdgcn_mfma_f32_16x16x32_bf16(af[tm], bfr[tn], acc[tm][tn], 0, 0, 0);
  }

  #pragma unroll
  for (int tn = 0; tn < 4; tn++){
    int col = bn*128 + wn*64 + tn*16 + m16;
    float bv = BIAS ? bias[col] : 0.0f;
    #pragma unroll
    for (int tm = 0; tm < 4; tm++){
      int row0 = bm*128 + wm*64 + tm*16 + quad*4;
      #pragma unroll
      for (int r = 0; r < 4; r++){
        int row = row0 + r;
        if (row < M){
          float v = acc[tm][tn][r] + bv;
          if (RELU) v = fmaxf(v, 0.0f);
          if (OUTBF16) ((unsigned short*)Cp)[(size_t)row*Nout + col] = f2bf(v);
          else         ((float*)Cp)[(size_t)row*Nout + col] = v;
        }
      }
    }
  }
}

// ---------------- LayerNorm (one wave per node) ----------------
__global__ __launch_bounds__(256) void k_ln(const float* h, const float* g, const float* b,
                                            unsigned short* nf, int N){
  const int lane = threadIdx.x & 63, wv = threadIdx.x >> 6;
  const int i = blockIdx.x*4 + wv;
  if (i >= N) return;
  const float* row = h + (size_t)i*256;
  float4 v = *(const float4*)(row + lane*4);
  float s = v.x + v.y + v.z + v.w;
  float q = v.x*v.x + v.y*v.y + v.z*v.z + v.w*v.w;
  for (int off = 32; off > 0; off >>= 1){
    s += __shfl_xor(s, off, 64);
    q += __shfl_xor(q, off, 64);
  }
  float mean = s * (1.0f/256.0f);
  float var  = q * (1.0f/256.0f) - mean*mean;
  float rs = rsqrtf(var + EPSV);
  int c = lane*4;
  ushort4 st;
  st.x = f2bf((v.x - mean)*rs*g[c+0] + b[c+0]);
  st.y = f2bf((v.y - mean)*rs*g[c+1] + b[c+1]);
  st.z = f2bf((v.z - mean)*rs*g[c+2] + b[c+2]);
  st.w = f2bf((v.w - mean)*rs*g[c+3] + b[c+3]);
  *(ushort4*)(nf + (size_t)i*256 + c) = st;
}

// ---------------- CSR aggregation: one wave per destination node ----------------
// Edges batched 64-wide per wave: one coalesced ep load, __shfl broadcast,
// 8-wide unrolled gathers for memory-level parallelism.
template<int D, bool BIAS>
__global__ __launch_bounds__(256) void k_agg(const unsigned short* xw, const int2* ep,
    const int* offs, const float* dis, const float* bias, float* out, int N){
  constexpr int V = D / 64;
  const int lane = threadIdx.x & 63, wv = threadIdx.x >> 6;
  const int i = blockIdx.x*4 + wv;
  if (i >= N) return;
  float acc[V];
  float dsi = dis[i];
  float coef = dsi * dsi;   // self-loop norm
  {
    const unsigned short* r = xw + (size_t)i*D + lane*V;
    if constexpr (V == 4){
      uint2 u = *(const uint2*)r;
      float a,b2,c,d; bf2x(u.x,a,b2); bf2x(u.y,c,d);
      acc[0]=coef*a; acc[1]=coef*b2; acc[2]=coef*c; acc[3]=coef*d;
    } else {
      unsigned int u = *(const unsigned int*)r;
      float a,b2; bf2x(u,a,b2);
      acc[0]=coef*a; acc[1]=coef*b2;
    }
  }
  const int e0 = offs[i], e1 = offs[i+1];
  for (int eb = e0; eb < e1; eb += 64){
    const int nb = min(64, e1 - eb);
    int2 pl = make_int2(0, 0);
    if (eb + lane < e1) pl = ep[eb + lane];
    int j = 0;
    for (; j + 8 <= nb; j += 8){
      int s0,s1,s2,s3,s4,s5,s6,s7;
      float n0,n1,n2,n3,n4,n5,n6,n7;
      s0=__shfl(pl.x,j+0,64); s1=__shfl(pl.x,j+1,64); s2=__shfl(pl.x,j+2,64); s3=__shfl(pl.x,j+3,64);
      s4=__shfl(pl.x,j+4,64); s5=__shfl(pl.x,j+5,64); s6=__shfl(pl.x,j+6,64); s7=__shfl(pl.x,j+7,64);
      n0=__int_as_float(__shfl(pl.y,j+0,64)); n1=__int_as_float(__shfl(pl.y,j+1,64));
      n2=__int_as_float(__shfl(pl.y,j+2,64)); n3=__int_as_float(__shfl(pl.y,j+3,64));
      n4=__int_as_float(__shfl(pl.y,j+4,64)); n5=__int_as_float(__shfl(pl.y,j+5,64));
      n6=__int_as_float(__shfl(pl.y,j+6,64)); n7=__int_as_float(__shfl(pl.y,j+7,64));
      if constexpr (V == 4){
        uint2 u0 = *(const uint2*)(xw + (size_t)s0*D + lane*V);
        uint2 u1 = *(const uint2*)(xw + (size_t)s1*D + lane*V);
        uint2 u2 = *(const uint2*)(xw + (size_t)s2*D + lane*V);
        uint2 u3 = *(const uint2*)(xw + (size_t)s3*D + lane*V);
        uint2 u4 = *(const uint2*)(xw + (size_t)s4*D + lane*V);
        uint2 u5 = *(const uint2*)(xw + (size_t)s5*D + lane*V);
        uint2 u6 = *(const uint2*)(xw + (size_t)s6*D + lane*V);
        uint2 u7 = *(const uint2*)(xw + (size_t)s7*D + lane*V);
        float a,b2,c,d;
        bf2x(u0.x,a,b2); bf2x(u0.y,c,d);
        acc[0]=fmaf(n0,a,acc[0]); acc[1]=fmaf(n0,b2,acc[1]); acc[2]=fmaf(n0,c,acc[2]); acc[3]=fmaf(n0,d,acc[3]);
        bf2x(u1.x,a,b2); bf2x(u1.y,c,d);
        acc[0]=fmaf(n1,a,acc[0]); acc[1]=fmaf(n1,b2,acc[1]); acc[2]=fmaf(n1,c,acc[2]); acc[3]=fmaf(n1,d,acc[3]);
        bf2x(u2.x,a,b2); bf2x(u2.y,c,d);
        acc[0]=fmaf(n2,a,acc[0]); acc[1]=fmaf(n2,b2,acc[1]); acc[2]=fmaf(n2,c,acc[2]); acc[3]=fmaf(n2,d,acc[3]);
        bf2x(u3.x,a,b2); bf2x(u3.y,c,d);
        acc[0]=fmaf(n3,a,acc[0]); acc[1]=fmaf(n3,b2,acc[1]); acc[2]=fmaf(n3,c,acc[2]); acc[3]=fmaf(n3,d,acc[3]);
        bf2x(u4.x,a,b2); bf2x(u4.y,c,d);
        acc[0]=fmaf(n4,a,acc[0]); acc[1]=fmaf(n4,b2,acc[1]); acc[2]=fmaf(n4,c,acc[2]); acc[3]=fmaf(n4,d,acc[3]);
        bf2x(u5.x,a,b2); bf2x(u5.y,c,d);
        acc[0]=fmaf(n5,a,acc[0]); acc[1]=fmaf(n5,b2,acc[1]); acc[2]=fmaf(n5,c,acc[2]); acc[3]=fmaf(n5,d,acc[3]);
        bf2x(u6.x,a,b2); bf2x(u6.y,c,d);
        acc[0]=fmaf(n6,a,acc[0]); acc[1]=fmaf(n6,b2,acc[1]); acc[2]=fmaf(n6,c,acc[2]); acc[3]=fmaf(n6,d,acc[3]);
        bf2x(u7.x,a,b2); bf2x(u7.y,c,d);
        acc[0]=fmaf(n7,a,acc[0]); acc[1]=fmaf(n7,b2,acc[1]); acc[2]=fmaf(n7,c,acc[2]); acc[3]=fmaf(n7,d,acc[3]);
      } else {
        unsigned int u0 = *(const unsigned int*)(xw + (size_t)s0*D + lane*V);
        unsigned int u1 = *(const unsigned int*)(xw + (size_t)s1*D + lane*V);
        unsigned int u2 = *(const unsigned int*)(xw + (size_t)s2*D + lane*V);
        unsigned int u3 = *(const unsigned int*)(xw + (size_t)s3*D + lane*V);
        unsigned int u4 = *(const unsigned int*)(xw + (size_t)s4*D + lane*V);
        unsigned int u5 = *(const unsigned int*)(xw + (size_t)s5*D + lane*V);
        unsigned int u6 = *(const unsigned int*)(xw + (size_t)s6*D + lane*V);
        unsigned int u7 = *(const unsigned int*)(xw + (size_t)s7*D + lane*V);
        float a,b2;
        bf2x(u0,a,b2); acc[0]=fmaf(n0,a,acc[0]); acc[1]=fmaf(n0,b2,acc[1]);
        bf2x(u1,a,b2); acc[0]=fmaf(n1,a,acc[0]); acc[1]=fmaf(n1,b2,acc[1]);
        bf2x(u2,a,b2); acc[0]=fmaf(n2,a,acc[0]); acc[1]=fmaf(n2,b2,acc[1]);
        bf2x(u3,a,b2); acc[0]=fmaf(n3,a,acc[0]); acc[1]=fmaf(n3,b2,acc[1]);
        bf2x(u4,a,b2); acc[0]=fmaf(n4,a,acc[0]); acc[1]=fmaf(n4,b2,acc[1]);
        bf2x(u5,a,b2); acc[0]=fmaf(n5,a,acc[0]); acc[1]=fmaf(n5,b2,acc[1]);
        bf2x(u6,a,b2); acc[0]=fmaf(n6,a,acc[0]); acc[1]=fmaf(n6,b2,acc[1]);
        bf2x(u7,a,b2); acc[0]=fmaf(n7,a,acc[0]); acc[1]=fmaf(n7,b2,acc[1]);
      }
    }
    for (; j < nb; j++){
      int   s0 = __shfl(pl.x, j, 64);
      float n0 = __int_as_float(__shfl(pl.y, j, 64));
      if constexpr (V == 4){
        uint2 u = *(const uint2*)(xw + (size_t)s0*D + lane*V);
        float a,b2,c,d; bf2x(u.x,a,b2); bf2x(u.y,c,d);
        acc[0]=fmaf(n0,a,acc[0]); acc[1]=fmaf(n0,b2,acc[1]);
        acc[2]=fmaf(n0,c,acc[2]); acc[3]=fmaf(n0,d,acc[3]);
      } else {
        unsigned int u = *(const unsigned int*)(xw + (size_t)s0*D + lane*V);
        float a,b2; bf2x(u,a,b2);
        acc[0]=fmaf(n0,a,acc[0]); acc[1]=fmaf(n0,b2,acc[1]);
      }
    }
  }
  float* o = out + (size_t)i*D + lane*V;
  if constexpr (V == 4){
    float4 st = make_float4(acc[0] + (BIAS?bias[lane*4+0]:0.f),
                            acc[1] + (BIAS?bias[lane*4+1]:0.f),
                            acc[2] + (BIAS?bias[lane*4+2]:0.f),
                            acc[3] + (BIAS?bias[lane*4+3]:0.f));
    *(float4*)o = st;
  } else {
    float2 st = make_float2(acc[0] + (BIAS?bias[lane*2+0]:0.f),
                            acc[1] + (BIAS?bias[lane*2+1]:0.f));
    *(float2*)o = st;
  }
}

// ---------------- BatchNorm stats: 512 blocks, float4 loads, atomic fp32 partials ----------------
__global__ __launch_bounds__(256) void k_stats(const float* xc, float* acc, int N){
  const int t  = threadIdx.x;
  const int c4 = t & 63;        // which float4 of the 256 channels
  const int rs = t >> 6;        // 0..3 row slice
  const int rows = (N + gridDim.x - 1) / gridDim.x;
  const int r0 = blockIdx.x * rows;
  const int r1 = min(r0 + rows, N);
  float4 s = make_float4(0,0,0,0), q = make_float4(0,0,0,0);
  for (int r = r0 + rs; r < r1; r += 4){
    float4 v = ((const float4*)(xc + (size_t)r*256))[c4];
    s.x += v.x; s.y += v.y; s.z += v.z; s.w += v.w;
    q.x = fmaf(v.x, v.x, q.x); q.y = fmaf(v.y, v.y, q.y);
    q.z = fmaf(v.z, v.z, q.z); q.w = fmaf(v.w, v.w, q.w);
  }
  __shared__ float4 sm[512];
  sm[t] = s; sm[256 + t] = q;
  __syncthreads();
  for (int off = 128; off >= 64; off >>= 1){
    if (t < off){
      float4 a = sm[t + off];       sm[t].x += a.x; sm[t].y += a.y; sm[t].z += a.z; sm[t].w += a.w;
      float4 b = sm[256 + t + off]; sm[256+t].x += b.x; sm[256+t].y += b.y; sm[256+t].z += b.z; sm[256+t].w += b.w;
    }
    __syncthreads();
  }
  if (t < 64){
    float4 sv = sm[t], qv = sm[256 + t];
    atomicAdd(&acc[t*4+0], sv.x); atomicAdd(&acc[t*4+1], sv.y);
    atomicAdd(&acc[t*4+2], sv.z); atomicAdd(&acc[t*4+3], sv.w);
    atomicAdd(&acc[256+t*4+0], qv.x); atomicAdd(&acc[256+t*4+1], qv.y);
    atomicAdd(&acc[256+t*4+2], qv.z); atomicAdd(&acc[256+t*4+3], qv.w);
  }
}

__global__ void k_bnfin(const float* acc, const float* g, const float* b, float* ss, int N){
  int ch = threadIdx.x;
  float mean = acc[ch] / (float)N;
  float var  = acc[256 + ch] / (float)N - mean*mean;   // biased var, matches reference
  float sc = g[ch] * rsqrtf(var + EPSV);
  ss[ch]       = sc;
  ss[256 + ch] = b[ch] - mean * sc;
}

// ---------------- BN apply + ReLU + residual (+ node_features on layer 0) ----------------
__global__ void k_apply(const float* xc, const float* ss, const float* resid,
                        const unsigned short* nf, float* outc, int total4){
  for (int idx = blockIdx.x*blockDim.x + threadIdx.x; idx < total4; idx += gridDim.x*blockDim.x){
    int cq = idx & 63;
    float4 v  = ((const float4*)xc)[idx];
    float4 sc = ((const float4*)ss)[cq];
    float4 sh = ((const float4*)ss)[64 + cq];
    float4 r  = ((const float4*)resid)[idx];
    float o0 = fmaxf(fmaf(v.x, sc.x, sh.x), 0.0f) + r.x;
    float o1 = fmaxf(fmaf(v.y, sc.y, sh.y), 0.0f) + r.y;
    float o2 = fmaxf(fmaf(v.z, sc.z, sh.z), 0.0f) + r.z;
    float o3 = fmaxf(fmaf(v.w, sc.w, sh.w), 0.0f) + r.w;
    if (nf){
      uint2 u = ((const uint2*)nf)[idx];
      float a,b2,c,d; bf2x(u.x,a,b2); bf2x(u.y,c,d);
      o0 += a; o1 += b2; o2 += c; o3 += d;
    }
    ((float4*)outc)[idx] = make_float4(o0, o1, o2, o3);
  }
}

// ---------------- global mean pool: 256 blocks, float4, LDS tree, atomic tail ----------------
__global__ __launch_bounds__(256) void k_graph(const float* ne, float* g, int N){
  const int t  = threadIdx.x;
  const int c4 = t & 31;        // which float4 of the 128 channels
  const int rs = t >> 5;        // 0..7 row slice
  const int rows = (N + gridDim.x - 1) / gridDim.x;
  const int r0 = blockIdx.x * rows;
  const int r1 = min(r0 + rows, N);
  float4 a = make_float4(0,0,0,0);
  for (int r = r0 + rs; r < r1; r += 8){
    float4 v = ((const float4*)(ne + (size_t)r*128))[c4];
    a.x += v.x; a.y += v.y; a.z += v.z; a.w += v.w;
  }
  __shared__ float4 sm[256];
  sm[t] = a;
  __syncthreads();
  for (int off = 128; off >= 32; off >>= 1){
    if (t < off){
      float4 b = sm[t + off];
      sm[t].x += b.x; sm[t].y += b.y; sm[t].z += b.z; sm[t].w += b.w;
    }
    __syncthreads();
  }
  if (t < 32){
    float4 v = sm[t];
    float inv = 1.0f / (float)N;
    atomicAdd(&g[t*4+0], v.x*inv); atomicAdd(&g[t*4+1], v.y*inv);
    atomicAdd(&g[t*4+2], v.z*inv); atomicAdd(&g[t*4+3], v.w*inv);
  }
}

extern "C" void kernel_launch(void* const* d_in, const int* in_sizes, int n_in,
                              void* d_out, int out_size, void* d_ws, size_t ws_size,
                              hipStream_t stream){
  const float* x     = (const float*)d_in[0];
  const int*   ei    = (const int*)d_in[1];     // harness passes integers as int32
  const float* ew    = (const float*)d_in[2];
  const float* W_nt1 = (const float*)d_in[3];
  const float* b_nt1 = (const float*)d_in[4];
  const float* W_nt2 = (const float*)d_in[5];
  const float* b_nt2 = (const float*)d_in[6];
  const float* ln_g  = (const float*)d_in[7];
  const float* ln_b  = (const float*)d_in[8];
  const float* Wc    = (const float*)d_in[9];
  // d_in[10] = bc (hidden conv bias): exactly cancelled by BN mean-subtraction — skipped
  const float* bn_g  = (const float*)d_in[11];
  const float* bn_b  = (const float*)d_in[12];
  const float* Wl    = (const float*)d_in[13];
  const float* bl    = (const float*)d_in[14];

  const int N = in_sizes[0] / 256;
  const int E = in_sizes[2];

  char* w = (char*)d_ws;
  size_t o = 0;
  auto alloc = [&](size_t bytes) -> void* {
    void* p = w + o;
    o = (o + bytes + 255) & ~(size_t)255;
    return p;
  };
  float* deg   = (float*)alloc((size_t)N*4);
  float* dis   = (float*)alloc((size_t)N*4);
  int*   cnt   = (int*)  alloc((size_t)N*4);   // reused as bucket cursor (zeroed in k_scan3)
  int*   offs  = (int*)  alloc((size_t)(N+1)*4);
  int*   part  = (int*)  alloc(64*4);
  int2*  ep    = (int2*) alloc((size_t)E*8);
  unsigned short* WT = (unsigned short*)alloc((size_t)6*65536*2);
  unsigned short* xw = (unsigned short*)alloc((size_t)N*256*2);  // also holds h1
  unsigned short* nf = (unsigned short*)alloc((size_t)N*256*2);
  float* xc   = (float*)alloc((size_t)N*256*4);                  // also holds h2
  float* cur  = (float*)alloc((size_t)N*256*4);
  float* bnacc = (float*)alloc(512*4);
  float* ss   = (float*)alloc(512*4);

  float* node_emb  = (float*)d_out;
  float* graph_emb = node_emb + (size_t)N*128;

  const int gN = (N + 255)/256, gE = (E + 255)/256, gW = (N + 3)/4;
  const int NB = (N + 1023)/1024;   // scan blocks (N=50000 -> 49, must be <= 64)

  hipMemsetAsync(graph_emb, 0, 128*sizeof(float), stream);
  k_init<<<gN, 256, 0, stream>>>(deg, cnt, N);
  k_deg <<<gE, 256, 0, stream>>>(ei, ew, deg, cnt, E);
  k_dis <<<gN, 256, 0, stream>>>(deg, dis, N);
  k_scan1<<<NB, 256, 0, stream>>>(cnt, part, N);
  k_scan2<<<1, 64, 0, stream>>>(part, offs, NB, N);
  k_scan3<<<NB, 256, 0, stream>>>(cnt, part, offs, N);
  k_bucket<<<gE, 256, 0, stream>>>(ei, ew, dis, offs, cnt, ep, E);
  k_wt  <<<256, 256, 0, stream>>>(W_nt1, W_nt2, Wc, Wl, WT);

  dim3 gg((N + 127)/128, 2);
  // node_transform: h1 = relu(x@W1+b1)  (bf16 out) ; h2 = h1@W2+b2 (fp32) ; LN -> nf (bf16)
  k_gemm<false, true,  true, true ><<<gg, 256, 0, stream>>>(x,  WT + 0*65536, b_nt1, xw, N, 256);
  k_gemm<true,  false, true, false><<<gg, 256, 0, stream>>>(xw, WT + 1*65536, b_nt2, xc, N, 256);
  k_ln<<<gW, 256, 0, stream>>>(xc, ln_g, ln_b, nf, N);

  for (int i = 0; i < 3; i++){
    const float* cin = (i == 0) ? x : cur;
    k_gemm<false, true, false, false><<<gg, 256, 0, stream>>>(cin, WT + (size_t)(2+i)*65536, nullptr, xw, N, 256);
    k_agg<256, false><<<gW, 256, 0, stream>>>(xw, ep, offs, dis, nullptr, xc, N);
    hipMemsetAsync(bnacc, 0, 512*sizeof(float), stream);
    k_stats<<<512, 256, 0, stream>>>(xc, bnacc, N);
    k_bnfin<<<1, 256, 0, stream>>>(bnacc, bn_g + i*256, bn_b + i*256, ss, N);
    k_apply<<<2048, 256, 0, stream>>>(xc, ss, cin, (i == 0) ? nf : nullptr, cur, N*64);
  }

  dim3 gl((N + 127)/128, 1);
  k_gemm<false, true, false, false><<<gl, 256, 0, stream>>>(cur, WT + (size_t)5*65536, nullptr, xw, N, 128);
  k_agg<128, true><<<gW, 256, 0, stream>>>(xw, ep, offs, dis, bl, node_emb, N);
  k_graph<<<256, 256, 0, stream>>>(node_emb, graph_emb, N);
}

// Round 5
// 877.282 us; speedup vs baseline: 1.5932x; 1.0441x over previous
//
#include <hip/hip_runtime.h>

#define EPSV 1e-5f

typedef __attribute__((ext_vector_type(8))) short v8s;
typedef __attribute__((ext_vector_type(4))) float v4f;

__device__ __forceinline__ unsigned short f2bf(float f){
  unsigned int u = __float_as_uint(f);
  u += 0x7FFF + ((u >> 16) & 1);
  return (unsigned short)(u >> 16);
}
__device__ __forceinline__ void bf2x(unsigned int u, float& lo, float& hi){
  lo = __uint_as_float(u << 16);
  hi = __uint_as_float(u & 0xffff0000u);
}

// ---------------- preprocessing ----------------
// NOTE: harness passes integer inputs as int32 (edge_index is [2,E] int32 here).
// deg+cnt packed in one u64 per node: [63:40]=edge count, [39:0]=fixed-point(2^24) weighted degree.
// Halves atomic ops and dirty-line writebacks vs two separate atomics (R4: 49.8MB WRITE_SIZE).
__global__ void k_init(unsigned long long* packed, int N){
  int i = blockIdx.x*256 + threadIdx.x;
  if (i < N) packed[i] = (1ULL << 24);   // deg = 1.0 (self-loop weight), cnt = 0
}

__global__ void k_deg(const int* ei, const float* ew, unsigned long long* packed, int E){
  int e = blockIdx.x*256 + threadIdx.x;
  if (e < E){
    int c = ei[E + e];
    unsigned long long inc = (1ULL << 40) | (unsigned long long)(ew[e] * 16777216.0f + 0.5f);
    atomicAdd(&packed[c], inc);
  }
}

__global__ void k_post(const unsigned long long* packed, float* dis, int* cnt, int N){
  int i = blockIdx.x*256 + threadIdx.x;
  if (i < N){
    unsigned long long p = packed[i];
    float deg = (float)(p & ((1ULL << 40) - 1)) * (1.0f/16777216.0f);
    dis[i] = rsqrtf(deg);   // deg >= 1 always
    cnt[i] = (int)(p >> 40);
  }
}

// ---------------- 3-phase coalesced exclusive scan over cnt[N] -> offs[N+1] ----------------
__global__ __launch_bounds__(256) void k_scan1(const int* cnt, int* part, int N){
  const int t = threadIdx.x, b = blockIdx.x;
  const int base = b*1024 + t*4;
  int4 v = make_int4(0,0,0,0);
  if (base + 3 < N) v = *(const int4*)(cnt + base);
  else {
    if (base   < N) v.x = cnt[base];
    if (base+1 < N) v.y = cnt[base+1];
    if (base+2 < N) v.z = cnt[base+2];
    if (base+3 < N) v.w = cnt[base+3];
  }
  int s = v.x + v.y + v.z + v.w;
  __shared__ int sm[256];
  sm[t] = s;
  __syncthreads();
  for (int off = 128; off > 0; off >>= 1){
    if (t < off) sm[t] += sm[t + off];
    __syncthreads();
  }
  if (t == 0) part[b] = sm[0];
}

__global__ __launch_bounds__(64) void k_scan2(int* part, int* offs, int NB, int N){
  const int t = threadIdx.x;
  int orig = (t < NB) ? part[t] : 0;
  int v = orig;
  for (int off = 1; off < 64; off <<= 1){
    int u = __shfl_up(v, off, 64);
    if (t >= off) v += u;
  }
  if (t < NB) part[t] = v - orig;   // exclusive block prefix
  if (t == 63) offs[N] = v;         // grand total = E
}

__global__ __launch_bounds__(256) void k_scan3(int* cnt, const int* part, int* offs, int N){
  const int t = threadIdx.x, b = blockIdx.x;
  const int base = b*1024 + t*4;
  int4 v = make_int4(0,0,0,0);
  if (base + 3 < N) v = *(const int4*)(cnt + base);
  else {
    if (base   < N) v.x = cnt[base];
    if (base+1 < N) v.y = cnt[base+1];
    if (base+2 < N) v.z = cnt[base+2];
    if (base+3 < N) v.w = cnt[base+3];
  }
  int s = v.x + v.y + v.z + v.w;
  __shared__ int sm[256];
  sm[t] = s;
  __syncthreads();
  for (int off = 1; off < 256; off <<= 1){
    int u = (t >= off) ? sm[t - off] : 0;
    __syncthreads();
    sm[t] += u;
    __syncthreads();
  }
  int run = part[b] + sm[t] - s;    // global exclusive prefix for this thread's chunk
  if (base   < N) offs[base]   = run; run += v.x;
  if (base+1 < N) offs[base+1] = run; run += v.y;
  if (base+2 < N) offs[base+2] = run; run += v.z;
  if (base+3 < N) offs[base+3] = run;
  // zero the cursor for k_bucket (each element touched by exactly one thread)
  if (base + 3 < N) *(int4*)(cnt + base) = make_int4(0,0,0,0);
  else {
    if (base   < N) cnt[base]   = 0;
    if (base+1 < N) cnt[base+1] = 0;
    if (base+2 < N) cnt[base+2] = 0;
  }
}

// cnt is reused as the per-node cursor (zeroed by k_scan3)
__global__ void k_bucket(const int* ei, const float* ew, const float* dis, const int* offs,
                         int* cursor, int2* ep, int E){
  int e = blockIdx.x*256 + threadIdx.x;
  if (e < E){
    int r = ei[e], c = ei[E + e];
    float nrm = dis[r] * ew[e] * dis[c];
    int pos = offs[c] + atomicAdd(&cursor[c], 1);
    ep[pos] = make_int2(r, __float_as_int(nrm));
  }
}

// fp32 -> bf16 cast (x), float4-wide
__global__ void k_cast(const float* x, unsigned short* xb, int total4){
  int idx = blockIdx.x*256 + threadIdx.x;
  if (idx < total4){
    float4 v = ((const float4*)x)[idx];
    ushort4 s;
    s.x = f2bf(v.x); s.y = f2bf(v.y); s.z = f2bf(v.z); s.w = f2bf(v.w);
    ((ushort4*)xb)[idx] = s;
  }
}

// transpose + bf16-convert all weights: [WT1|WT2|WTc0|WTc1|WTc2|WTlast], each [n][k], k-stride 256
__global__ void k_wt(const float* W1, const float* W2, const float* Wc, const float* Wl,
                     unsigned short* WT){
  int t = blockIdx.x*256 + threadIdx.x;   // 65536 threads
  int k = t >> 8, n = t & 255;
  WT[0*65536 + n*256 + k] = f2bf(W1[k*256 + n]);
  WT[1*65536 + n*256 + k] = f2bf(W2[k*256 + n]);
  WT[2*65536 + n*256 + k] = f2bf(Wc[0*65536 + k*256 + n]);
  WT[3*65536 + n*256 + k] = f2bf(Wc[1*65536 + k*256 + n]);
  WT[4*65536 + n*256 + k] = f2bf(Wc[2*65536 + k*256 + n]);
  if (n < 128) WT[5*65536 + n*256 + k] = f2bf(Wl[k*128 + n]);
}

// ---------------- bf16 MFMA GEMM: C[M,Nout] = A[M,256] * W[256,Nout] ----------------
// A is bf16 [M][256]; WT is bf16 [Nout][256].
template<bool OUTBF16, bool BIAS, bool RELU>
__global__ __launch_bounds__(256, 3) void k_gemm(const unsigned short* A, const unsigned short* WT,
    const float* bias, void* Cp, int M, int Nout){
  __shared__ unsigned short As[128][40];
  __shared__ unsigned short Bs[128][40];
  const int tid  = threadIdx.x;
  const int lane = tid & 63, wv = tid >> 6;
  const int wm = wv >> 1, wn = wv & 1;
  const int quad = lane >> 4, m16 = lane & 15;
  const int bm = blockIdx.x, bn = blockIdx.y;
  const int srow = tid >> 1, sseg = (tid & 1) * 16;
  const int arow_g = min(bm*128 + srow, M - 1);

  v4f acc[4][4];
  #pragma unroll
  for (int a = 0; a < 4; a++)
    #pragma unroll
    for (int b = 0; b < 4; b++) acc[a][b] = (v4f)(0.0f);

  for (int ks = 0; ks < 256; ks += 32){
    __syncthreads();
    {
      const unsigned short* src = A + (size_t)arow_g*256 + ks + sseg;
      uint4 u0 = *(const uint4*)(src);
      uint4 u1 = *(const uint4*)(src + 8);
      *(uint4*)&As[srow][sseg]     = u0;
      *(uint4*)&As[srow][sseg + 8] = u1;
    }
    {
      const unsigned short* src = WT + (size_t)(bn*128 + srow)*256 + ks + sseg;
      uint4 u0 = *(const uint4*)(src);
      uint4 u1 = *(const uint4*)(src + 8);
      *(uint4*)&Bs[srow][sseg]     = u0;
      *(uint4*)&Bs[srow][sseg + 8] = u1;
    }
    __syncthreads();

    v8s af[4], bfr[4];
    #pragma unroll
    for (int tm = 0; tm < 4; tm++) af[tm]  = *(const v8s*)&As[wm*64 + tm*16 + m16][quad*8];
    #pragma unroll
    for (int tn = 0; tn < 4; tn++) bfr[tn] = *(const v8s*)&Bs[wn*64 + tn*16 + m16][quad*8];
    #pragma unroll
    for (int tm = 0; tm < 4; tm++)
      #pragma unroll
      for (int tn = 0; tn < 4; tn++)
        acc[tm][tn] = __builtin_amdgcn_mfma_f32_16x16x32_bf16(af[tm], bfr[tn], acc[tm][tn], 0, 0, 0);
  }

  #pragma unroll
  for (int tn = 0; tn < 4; tn++){
    int col = bn*128 + wn*64 + tn*16 + m16;
    float bv = BIAS ? bias[col] : 0.0f;
    #pragma unroll
    for (int tm = 0; tm < 4; tm++){
      int row0 = bm*128 + wm*64 + tm*16 + quad*4;
      #pragma unroll
      for (int r = 0; r < 4; r++){
        int row = row0 + r;
        if (row < M){
          float v = acc[tm][tn][r] + bv;
          if (RELU) v = fmaxf(v, 0.0f);
          if (OUTBF16) ((unsigned short*)Cp)[(size_t)row*Nout + col] = f2bf(v);
          else         ((float*)Cp)[(size_t)row*Nout + col] = v;
        }
      }
    }
  }
}

// ---------------- LayerNorm (one wave per node) ----------------
__global__ __launch_bounds__(256) void k_ln(const float* h, const float* g, const float* b,
                                            unsigned short* nf, int N){
  const int lane = threadIdx.x & 63, wv = threadIdx.x >> 6;
  const int i = blockIdx.x*4 + wv;
  if (i >= N) return;
  const float* row = h + (size_t)i*256;
  float4 v = *(const float4*)(row + lane*4);
  float s = v.x + v.y + v.z + v.w;
  float q = v.x*v.x + v.y*v.y + v.z*v.z + v.w*v.w;
  for (int off = 32; off > 0; off >>= 1){
    s += __shfl_xor(s, off, 64);
    q += __shfl_xor(q, off, 64);
  }
  float mean = s * (1.0f/256.0f);
  float var  = q * (1.0f/256.0f) - mean*mean;
  float rs = rsqrtf(var + EPSV);
  int c = lane*4;
  ushort4 st;
  st.x = f2bf((v.x - mean)*rs*g[c+0] + b[c+0]);
  st.y = f2bf((v.y - mean)*rs*g[c+1] + b[c+1]);
  st.z = f2bf((v.z - mean)*rs*g[c+2] + b[c+2]);
  st.w = f2bf((v.w - mean)*rs*g[c+3] + b[c+3]);
  *(ushort4*)(nf + (size_t)i*256 + c) = st;
}

// ---------------- CSR aggregation: one wave per destination node ----------------
template<int D, bool BIAS>
__global__ __launch_bounds__(256) void k_agg(const unsigned short* xw, const int2* ep,
    const int* offs, const float* dis, const float* bias, float* out, int N){
  constexpr int V = D / 64;
  const int lane = threadIdx.x & 63, wv = threadIdx.x >> 6;
  const int i = blockIdx.x*4 + wv;
  if (i >= N) return;
  float acc[V];
  float dsi = dis[i];
  float coef = dsi * dsi;   // self-loop norm
  {
    const unsigned short* r = xw + (size_t)i*D + lane*V;
    if constexpr (V == 4){
      uint2 u = *(const uint2*)r;
      float a,b2,c,d; bf2x(u.x,a,b2); bf2x(u.y,c,d);
      acc[0]=coef*a; acc[1]=coef*b2; acc[2]=coef*c; acc[3]=coef*d;
    } else {
      unsigned int u = *(const unsigned int*)r;
      float a,b2; bf2x(u,a,b2);
      acc[0]=coef*a; acc[1]=coef*b2;
    }
  }
  const int e0 = offs[i], e1 = offs[i+1];
  for (int eb = e0; eb < e1; eb += 64){
    const int nb = min(64, e1 - eb);
    int2 pl = make_int2(0, 0);
    if (eb + lane < e1) pl = ep[eb + lane];
    int j = 0;
    for (; j + 8 <= nb; j += 8){
      int s0,s1,s2,s3,s4,s5,s6,s7;
      float n0,n1,n2,n3,n4,n5,n6,n7;
      s0=__shfl(pl.x,j+0,64); s1=__shfl(pl.x,j+1,64); s2=__shfl(pl.x,j+2,64); s3=__shfl(pl.x,j+3,64);
      s4=__shfl(pl.x,j+4,64); s5=__shfl(pl.x,j+5,64); s6=__shfl(pl.x,j+6,64); s7=__shfl(pl.x,j+7,64);
      n0=__int_as_float(__shfl(pl.y,j+0,64)); n1=__int_as_float(__shfl(pl.y,j+1,64));
      n2=__int_as_float(__shfl(pl.y,j+2,64)); n3=__int_as_float(__shfl(pl.y,j+3,64));
      n4=__int_as_float(__shfl(pl.y,j+4,64)); n5=__int_as_float(__shfl(pl.y,j+5,64));
      n6=__int_as_float(__shfl(pl.y,j+6,64)); n7=__int_as_float(__shfl(pl.y,j+7,64));
      if constexpr (V == 4){
        uint2 u0 = *(const uint2*)(xw + (size_t)s0*D + lane*V);
        uint2 u1 = *(const uint2*)(xw + (size_t)s1*D + lane*V);
        uint2 u2 = *(const uint2*)(xw + (size_t)s2*D + lane*V);
        uint2 u3 = *(const uint2*)(xw + (size_t)s3*D + lane*V);
        uint2 u4 = *(const uint2*)(xw + (size_t)s4*D + lane*V);
        uint2 u5 = *(const uint2*)(xw + (size_t)s5*D + lane*V);
        uint2 u6 = *(const uint2*)(xw + (size_t)s6*D + lane*V);
        uint2 u7 = *(const uint2*)(xw + (size_t)s7*D + lane*V);
        float a,b2,c,d;
        bf2x(u0.x,a,b2); bf2x(u0.y,c,d);
        acc[0]=fmaf(n0,a,acc[0]); acc[1]=fmaf(n0,b2,acc[1]); acc[2]=fmaf(n0,c,acc[2]); acc[3]=fmaf(n0,d,acc[3]);
        bf2x(u1.x,a,b2); bf2x(u1.y,c,d);
        acc[0]=fmaf(n1,a,acc[0]); acc[1]=fmaf(n1,b2,acc[1]); acc[2]=fmaf(n1,c,acc[2]); acc[3]=fmaf(n1,d,acc[3]);
        bf2x(u2.x,a,b2); bf2x(u2.y,c,d);
        acc[0]=fmaf(n2,a,acc[0]); acc[1]=fmaf(n2,b2,acc[1]); acc[2]=fmaf(n2,c,acc[2]); acc[3]=fmaf(n2,d,acc[3]);
        bf2x(u3.x,a,b2); bf2x(u3.y,c,d);
        acc[0]=fmaf(n3,a,acc[0]); acc[1]=fmaf(n3,b2,acc[1]); acc[2]=fmaf(n3,c,acc[2]); acc[3]=fmaf(n3,d,acc[3]);
        bf2x(u4.x,a,b2); bf2x(u4.y,c,d);
        acc[0]=fmaf(n4,a,acc[0]); acc[1]=fmaf(n4,b2,acc[1]); acc[2]=fmaf(n4,c,acc[2]); acc[3]=fmaf(n4,d,acc[3]);
        bf2x(u5.x,a,b2); bf2x(u5.y,c,d);
        acc[0]=fmaf(n5,a,acc[0]); acc[1]=fmaf(n5,b2,acc[1]); acc[2]=fmaf(n5,c,acc[2]); acc[3]=fmaf(n5,d,acc[3]);
        bf2x(u6.x,a,b2); bf2x(u6.y,c,d);
        acc[0]=fmaf(n6,a,acc[0]); acc[1]=fmaf(n6,b2,acc[1]); acc[2]=fmaf(n6,c,acc[2]); acc[3]=fmaf(n6,d,acc[3]);
        bf2x(u7.x,a,b2); bf2x(u7.y,c,d);
        acc[0]=fmaf(n7,a,acc[0]); acc[1]=fmaf(n7,b2,acc[1]); acc[2]=fmaf(n7,c,acc[2]); acc[3]=fmaf(n7,d,acc[3]);
      } else {
        unsigned int u0 = *(const unsigned int*)(xw + (size_t)s0*D + lane*V);
        unsigned int u1 = *(const unsigned int*)(xw + (size_t)s1*D + lane*V);
        unsigned int u2 = *(const unsigned int*)(xw + (size_t)s2*D + lane*V);
        unsigned int u3 = *(const unsigned int*)(xw + (size_t)s3*D + lane*V);
        unsigned int u4 = *(const unsigned int*)(xw + (size_t)s4*D + lane*V);
        unsigned int u5 = *(const unsigned int*)(xw + (size_t)s5*D + lane*V);
        unsigned int u6 = *(const unsigned int*)(xw + (size_t)s6*D + lane*V);
        unsigned int u7 = *(const unsigned int*)(xw + (size_t)s7*D + lane*V);
        float a,b2;
        bf2x(u0,a,b2); acc[0]=fmaf(n0,a,acc[0]); acc[1]=fmaf(n0,b2,acc[1]);
        bf2x(u1,a,b2); acc[0]=fmaf(n1,a,acc[0]); acc[1]=fmaf(n1,b2,acc[1]);
        bf2x(u2,a,b2); acc[0]=fmaf(n2,a,acc[0]); acc[1]=fmaf(n2,b2,acc[1]);
        bf2x(u3,a,b2); acc[0]=fmaf(n3,a,acc[0]); acc[1]=fmaf(n3,b2,acc[1]);
        bf2x(u4,a,b2); acc[0]=fmaf(n4,a,acc[0]); acc[1]=fmaf(n4,b2,acc[1]);
        bf2x(u5,a,b2); acc[0]=fmaf(n5,a,acc[0]); acc[1]=fmaf(n5,b2,acc[1]);
        bf2x(u6,a,b2); acc[0]=fmaf(n6,a,acc[0]); acc[1]=fmaf(n6,b2,acc[1]);
        bf2x(u7,a,b2); acc[0]=fmaf(n7,a,acc[0]); acc[1]=fmaf(n7,b2,acc[1]);
      }
    }
    for (; j < nb; j++){
      int   s0 = __shfl(pl.x, j, 64);
      float n0 = __int_as_float(__shfl(pl.y, j, 64));
      if constexpr (V == 4){
        uint2 u = *(const uint2*)(xw + (size_t)s0*D + lane*V);
        float a,b2,c,d; bf2x(u.x,a,b2); bf2x(u.y,c,d);
        acc[0]=fmaf(n0,a,acc[0]); acc[1]=fmaf(n0,b2,acc[1]);
        acc[2]=fmaf(n0,c,acc[2]); acc[3]=fmaf(n0,d,acc[3]);
      } else {
        unsigned int u = *(const unsigned int*)(xw + (size_t)s0*D + lane*V);
        float a,b2; bf2x(u,a,b2);
        acc[0]=fmaf(n0,a,acc[0]); acc[1]=fmaf(n0,b2,acc[1]);
      }
    }
  }
  float* o = out + (size_t)i*D + lane*V;
  if constexpr (V == 4){
    float4 st = make_float4(acc[0] + (BIAS?bias[lane*4+0]:0.f),
                            acc[1] + (BIAS?bias[lane*4+1]:0.f),
                            acc[2] + (BIAS?bias[lane*4+2]:0.f),
                            acc[3] + (BIAS?bias[lane*4+3]:0.f));
    *(float4*)o = st;
  } else {
    float2 st = make_float2(acc[0] + (BIAS?bias[lane*2+0]:0.f),
                            acc[1] + (BIAS?bias[lane*2+1]:0.f));
    *(float2*)o = st;
  }
}

// ---------------- BatchNorm stats: 512 blocks, float4 loads, atomic fp32 partials ----------------
__global__ __launch_bounds__(256) void k_stats(const float* xc, float* acc, int N){
  const int t  = threadIdx.x;
  const int c4 = t & 63;        // which float4 of the 256 channels
  const int rs = t >> 6;        // 0..3 row slice
  const int rows = (N + gridDim.x - 1) / gridDim.x;
  const int r0 = blockIdx.x * rows;
  const int r1 = min(r0 + rows, N);
  float4 s = make_float4(0,0,0,0), q = make_float4(0,0,0,0);
  for (int r = r0 + rs; r < r1; r += 4){
    float4 v = ((const float4*)(xc + (size_t)r*256))[c4];
    s.x += v.x; s.y += v.y; s.z += v.z; s.w += v.w;
    q.x = fmaf(v.x, v.x, q.x); q.y = fmaf(v.y, v.y, q.y);
    q.z = fmaf(v.z, v.z, q.z); q.w = fmaf(v.w, v.w, q.w);
  }
  __shared__ float4 sm[512];
  sm[t] = s; sm[256 + t] = q;
  __syncthreads();
  for (int off = 128; off >= 64; off >>= 1){
    if (t < off){
      float4 a = sm[t + off];       sm[t].x += a.x; sm[t].y += a.y; sm[t].z += a.z; sm[t].w += a.w;
      float4 b = sm[256 + t + off]; sm[256+t].x += b.x; sm[256+t].y += b.y; sm[256+t].z += b.z; sm[256+t].w += b.w;
    }
    __syncthreads();
  }
  if (t < 64){
    float4 sv = sm[t], qv = sm[256 + t];
    atomicAdd(&acc[t*4+0], sv.x); atomicAdd(&acc[t*4+1], sv.y);
    atomicAdd(&acc[t*4+2], sv.z); atomicAdd(&acc[t*4+3], sv.w);
    atomicAdd(&acc[256+t*4+0], qv.x); atomicAdd(&acc[256+t*4+1], qv.y);
    atomicAdd(&acc[256+t*4+2], qv.z); atomicAdd(&acc[256+t*4+3], qv.w);
  }
}

__global__ void k_bnfin(const float* acc, const float* g, const float* b, float* ss, int N){
  int ch = threadIdx.x;
  float mean = acc[ch] / (float)N;
  float var  = acc[256 + ch] / (float)N - mean*mean;   // biased var, matches reference
  float sc = g[ch] * rsqrtf(var + EPSV);
  ss[ch]       = sc;
  ss[256 + ch] = b[ch] - mean * sc;
}

// ---------------- BN apply + ReLU + residual (+ node_features on layer 0) ----------------
// Dual write: fp32 cur (residual path) + bf16 curbf (next GEMM's A input).
__global__ void k_apply(const float* xc, const float* ss, const float* resid,
                        const unsigned short* nf, float* outc, unsigned short* outb, int total4){
  for (int idx = blockIdx.x*blockDim.x + threadIdx.x; idx < total4; idx += gridDim.x*blockDim.x){
    int cq = idx & 63;
    float4 v  = ((const float4*)xc)[idx];
    float4 sc = ((const float4*)ss)[cq];
    float4 sh = ((const float4*)ss)[64 + cq];
    float4 r  = ((const float4*)resid)[idx];
    float o0 = fmaxf(fmaf(v.x, sc.x, sh.x), 0.0f) + r.x;
    float o1 = fmaxf(fmaf(v.y, sc.y, sh.y), 0.0f) + r.y;
    float o2 = fmaxf(fmaf(v.z, sc.z, sh.z), 0.0f) + r.z;
    float o3 = fmaxf(fmaf(v.w, sc.w, sh.w), 0.0f) + r.w;
    if (nf){
      uint2 u = ((const uint2*)nf)[idx];
      float a,b2,c,d; bf2x(u.x,a,b2); bf2x(u.y,c,d);
      o0 += a; o1 += b2; o2 += c; o3 += d;
    }
    ((float4*)outc)[idx] = make_float4(o0, o1, o2, o3);
    ushort4 s4; s4.x = f2bf(o0); s4.y = f2bf(o1); s4.z = f2bf(o2); s4.w = f2bf(o3);
    ((ushort4*)outb)[idx] = s4;
  }
}

// ---------------- global mean pool: 256 blocks, float4, LDS tree, atomic tail ----------------
__global__ __launch_bounds__(256) void k_graph(const float* ne, float* g, int N){
  const int t  = threadIdx.x;
  const int c4 = t & 31;        // which float4 of the 128 channels
  const int rs = t >> 5;        // 0..7 row slice
  const int rows = (N + gridDim.x - 1) / gridDim.x;
  const int r0 = blockIdx.x * rows;
  const int r1 = min(r0 + rows, N);
  float4 a = make_float4(0,0,0,0);
  for (int r = r0 + rs; r < r1; r += 8){
    float4 v = ((const float4*)(ne + (size_t)r*128))[c4];
    a.x += v.x; a.y += v.y; a.z += v.z; a.w += v.w;
  }
  __shared__ float4 sm[256];
  sm[t] = a;
  __syncthreads();
  for (int off = 128; off >= 32; off >>= 1){
    if (t < off){
      float4 b = sm[t + off];
      sm[t].x += b.x; sm[t].y += b.y; sm[t].z += b.z; sm[t].w += b.w;
    }
    __syncthreads();
  }
  if (t < 32){
    float4 v = sm[t];
    float inv = 1.0f / (float)N;
    atomicAdd(&g[t*4+0], v.x*inv); atomicAdd(&g[t*4+1], v.y*inv);
    atomicAdd(&g[t*4+2], v.z*inv); atomicAdd(&g[t*4+3], v.w*inv);
  }
}

extern "C" void kernel_launch(void* const* d_in, const int* in_sizes, int n_in,
                              void* d_out, int out_size, void* d_ws, size_t ws_size,
                              hipStream_t stream){
  const float* x     = (const float*)d_in[0];
  const int*   ei    = (const int*)d_in[1];     // harness passes integers as int32
  const float* ew    = (const float*)d_in[2];
  const float* W_nt1 = (const float*)d_in[3];
  const float* b_nt1 = (const float*)d_in[4];
  const float* W_nt2 = (const float*)d_in[5];
  const float* b_nt2 = (const float*)d_in[6];
  const float* ln_g  = (const float*)d_in[7];
  const float* ln_b  = (const float*)d_in[8];
  const float* Wc    = (const float*)d_in[9];
  // d_in[10] = bc (hidden conv bias): exactly cancelled by BN mean-subtraction — skipped
  const float* bn_g  = (const float*)d_in[11];
  const float* bn_b  = (const float*)d_in[12];
  const float* Wl    = (const float*)d_in[13];
  const float* bl    = (const float*)d_in[14];

  const int N = in_sizes[0] / 256;
  const int E = in_sizes[2];

  char* w = (char*)d_ws;
  size_t o = 0;
  auto alloc = [&](size_t bytes) -> void* {
    void* p = w + o;
    o = (o + bytes + 255) & ~(size_t)255;
    return p;
  };
  unsigned long long* packed = (unsigned long long*)alloc((size_t)N*8);
  float* dis   = (float*)alloc((size_t)N*4);
  int*   cnt   = (int*)  alloc((size_t)N*4);   // reused as bucket cursor (zeroed in k_scan3)
  int*   offs  = (int*)  alloc((size_t)(N+1)*4);
  int*   part  = (int*)  alloc(64*4);
  int2*  ep    = (int2*) alloc((size_t)E*8);
  unsigned short* WT = (unsigned short*)alloc((size_t)6*65536*2);
  unsigned short* xbf = (unsigned short*)alloc((size_t)N*256*2); // bf16 copy of x
  unsigned short* xw  = (unsigned short*)alloc((size_t)N*256*2); // GEMM bf16 outputs (h1/xw)
  unsigned short* nf  = (unsigned short*)alloc((size_t)N*256*2);
  unsigned short* curbf = (unsigned short*)alloc((size_t)N*256*2); // bf16 copy of cur
  float* xc   = (float*)alloc((size_t)N*256*4);                  // also holds h2
  float* cur  = (float*)alloc((size_t)N*256*4);
  float* bnacc = (float*)alloc(512*4);
  float* ss   = (float*)alloc(512*4);

  float* node_emb  = (float*)d_out;
  float* graph_emb = node_emb + (size_t)N*128;

  const int gN = (N + 255)/256, gE = (E + 255)/256, gW = (N + 3)/4;
  const int NB = (N + 1023)/1024;   // scan blocks (N=50000 -> 49, must be <= 64)

  hipMemsetAsync(graph_emb, 0, 128*sizeof(float), stream);
  k_init<<<gN, 256, 0, stream>>>(packed, N);
  k_deg <<<gE, 256, 0, stream>>>(ei, ew, packed, E);
  k_post<<<gN, 256, 0, stream>>>(packed, dis, cnt, N);
  k_scan1<<<NB, 256, 0, stream>>>(cnt, part, N);
  k_scan2<<<1, 64, 0, stream>>>(part, offs, NB, N);
  k_scan3<<<NB, 256, 0, stream>>>(cnt, part, offs, N);
  k_bucket<<<gE, 256, 0, stream>>>(ei, ew, dis, offs, cnt, ep, E);
  k_wt  <<<256, 256, 0, stream>>>(W_nt1, W_nt2, Wc, Wl, WT);
  k_cast<<<(N*64 + 255)/256, 256, 0, stream>>>(x, xbf, N*64);

  dim3 gg((N + 127)/128, 2);
  // node_transform: h1 = relu(x@W1+b1)  (bf16 out) ; h2 = h1@W2+b2 (fp32) ; LN -> nf (bf16)
  k_gemm<true,  true, true ><<<gg, 256, 0, stream>>>(xbf, WT + 0*65536, b_nt1, xw, N, 256);
  k_gemm<false, true, false><<<gg, 256, 0, stream>>>(xw,  WT + 1*65536, b_nt2, xc, N, 256);
  k_ln<<<gW, 256, 0, stream>>>(xc, ln_g, ln_b, nf, N);

  for (int i = 0; i < 3; i++){
    const unsigned short* ain = (i == 0) ? xbf : curbf;
    const float* rin = (i == 0) ? x : cur;
    k_gemm<true, false, false><<<gg, 256, 0, stream>>>(ain, WT + (size_t)(2+i)*65536, nullptr, xw, N, 256);
    k_agg<256, false><<<gW, 256, 0, stream>>>(xw, ep, offs, dis, nullptr, xc, N);
    hipMemsetAsync(bnacc, 0, 512*sizeof(float), stream);
    k_stats<<<512, 256, 0, stream>>>(xc, bnacc, N);
    k_bnfin<<<1, 256, 0, stream>>>(bnacc, bn_g + i*256, bn_b + i*256, ss, N);
    k_apply<<<2048, 256, 0, stream>>>(xc, ss, rin, (i == 0) ? nf : nullptr, cur, curbf, N*64);
  }

  dim3 gl((N + 127)/128, 1);
  k_gemm<true, false, false><<<gl, 256, 0, stream>>>(curbf, WT + (size_t)5*65536, nullptr, xw, N, 128);
  k_agg<128, true><<<gW, 256, 0, stream>>>(xw, ep, offs, dis, bl, node_emb, N);
  k_graph<<<256, 256, 0, stream>>>(node_emb, graph_emb, N);
}